// Round 9
// baseline (244.485 us; speedup 1.0000x reference)
//
#include <hip/hip_runtime.h>

#define T_TOK 16384
#define C_DIM 1024

typedef float f32x4 __attribute__((ext_vector_type(4)));
typedef float f32x16 __attribute__((ext_vector_type(16)));
typedef __bf16 bf16x8 __attribute__((ext_vector_type(8)));
typedef unsigned short u16x8 __attribute__((ext_vector_type(8)));
typedef unsigned short u16x4 __attribute__((ext_vector_type(4)));

__device__ __forceinline__ unsigned short f2bf(float f) {
  union { float f; unsigned u; } v; v.f = f;
  unsigned r = v.u + 0x7fffu + ((v.u >> 16) & 1u);
  return (unsigned short)(r >> 16);
}
__device__ __forceinline__ float bf2f(unsigned short h) {
  union { unsigned u; float f; } v; v.u = ((unsigned)h) << 16;
  return v.f;
}
__device__ __forceinline__ unsigned pk2(float a, float b) {
  return (unsigned)f2bf(a) | ((unsigned)f2bf(b) << 16);
}

// ---------------- f32 -> bf16 weight conversion ----------------
__global__ __launch_bounds__(256) void cvt_kernel(const float* __restrict__ in,
                                                  unsigned short* __restrict__ out, int n4) {
  int i = blockIdx.x * 256 + threadIdx.x;
  if (i >= n4) return;
  f32x4 v = *(const f32x4*)(in + (size_t)i * 4);
  u16x4 o;
#pragma unroll
  for (int j = 0; j < 4; ++j) o[j] = f2bf(v[j]);
  *(u16x4*)(out + (size_t)i * 4) = o;
}

// ---------------- RoPE table: [32 pos][32 dmod] float2 (cos,sin) ----------------
__global__ __launch_bounds__(256) void rope_tab_kernel(float* __restrict__ tab) {
  int idx = blockIdx.x * 256 + threadIdx.x;
  if (idx >= 1024) return;
  int mm = idx >> 5, d = idx & 31;
  float invf = powf(10000.f, -(float)d * (1.f / 32.f));
  float ang = (float)mm * invf;
  float s, c;
  sincosf(ang, &s, &c);
  tab[idx * 2] = c;
  tab[idx * 2 + 1] = s;
}

// ---------------- LayerNorm stats: mean/rstd per token ----------------
__global__ __launch_bounds__(256) void ln_stats_kernel(const float* __restrict__ x,
                                                       float* __restrict__ mu,
                                                       float* __restrict__ rstd) {
  __shared__ float s1[4][64];
  __shared__ float s2[4][64];
  const int tid = threadIdx.x;
  const int lt = tid & 63, cq = tid >> 6;
  const int t = blockIdx.x * 64 + lt;
  float s = 0.f, ss = 0.f;
  const float* p = x + (size_t)cq * 256 * T_TOK + t;
  for (int c = 0; c < 256; ++c) {
    float v = p[(size_t)c * T_TOK];
    s += v; ss += v * v;
  }
  s1[cq][lt] = s; s2[cq][lt] = ss;
  __syncthreads();
  if (tid < 64) {
    float S  = s1[0][tid] + s1[1][tid] + s1[2][tid] + s1[3][tid];
    float SS = s2[0][tid] + s2[1][tid] + s2[2][tid] + s2[3][tid];
    float m = S * (1.f / 1024.f);
    float var = SS * (1.f / 1024.f) - m * m;
    mu[blockIdx.x * 64 + tid] = m;
    rstd[blockIdx.x * 64 + tid] = rsqrtf(var + 1e-5f);
  }
}

// ---------------- LN apply + transpose: x (C,T) -> normed (T,C) bf16 ----------------
__global__ __launch_bounds__(256) void ln_tr_kernel(const float* __restrict__ x,
                                                    const float* __restrict__ mu,
                                                    const float* __restrict__ rstd,
                                                    const float* __restrict__ gamma,
                                                    const float* __restrict__ beta,
                                                    unsigned short* __restrict__ normed) {
  __shared__ float tile[64][65];
  __shared__ float gs[64], bs[64], ms[64], rs[64];
  const int tid = threadIdx.x;
  const int bt = blockIdx.x & 255;
  const int bc = blockIdx.x >> 8;
  const int t0 = bt * 64, c0 = bc * 64;
  if (tid < 64) {
    gs[tid] = gamma[c0 + tid];
    bs[tid] = beta[c0 + tid];
    ms[tid] = mu[t0 + tid];
    rs[tid] = rstd[t0 + tid];
  }
  const int lc = tid >> 4;
  const int lt4 = (tid & 15) * 4;
#pragma unroll
  for (int r = 0; r < 4; ++r) {
    int c = r * 16 + lc;
    f32x4 v = *(const f32x4*)&x[(size_t)(c0 + c) * T_TOK + t0 + lt4];
    tile[c][lt4 + 0] = v[0]; tile[c][lt4 + 1] = v[1];
    tile[c][lt4 + 2] = v[2]; tile[c][lt4 + 3] = v[3];
  }
  __syncthreads();
#pragma unroll
  for (int r = 0; r < 2; ++r) {
    int idx = r * 256 + tid;
    int t = idx >> 3;
    int c8 = (idx & 7) * 8;
    float m = ms[t], rr = rs[t];
    u16x8 o;
#pragma unroll
    for (int j = 0; j < 8; ++j) {
      float v = tile[c8 + j][t];
      v = (v - m) * rr * gs[c8 + j] + bs[c8 + j];
      o[j] = f2bf(v);
    }
    *(u16x8*)&normed[(size_t)(t0 + t) * C_DIM + c0 + c8] = o;
  }
}

#define GLDS(gp, lp) \
  __builtin_amdgcn_global_load_lds((const __attribute__((address_space(1))) void*)(gp), \
                                   (__attribute__((address_space(3))) void*)(lp), 16, 0, 0)

#define BARF() do { __builtin_amdgcn_s_barrier(); asm volatile("" ::: "memory"); } while (0)
#define VMC(n) asm volatile("s_waitcnt vmcnt(" #n ")" ::: "memory")

// ================= 256x256 bf16 NT GEMM, 32x32x16 MFMA =================
// C = A * B^T, A: MxK row-major bf16, B: NxK row-major bf16.
// EPI 0: bf16 out (ld=ldo) via wave-private LDS repack (GEMM1: qkv).
// EPI 1: f32 out at C[row][col] = Ofp[row*T_TOK+col] + Xadd (GEMM2': A=w_out,
//        B=aout -> C' = w_out @ aout^T = d_out layout directly; coalesced).
// 512 threads = 8 waves (2M x 4N); per-wave C: 128x64 (4x2 tiles of 32x32);
// BK=64; LDS 128 KiB dbuf. R8 quadrant schedule: reads up front, 4 MFMA
// clusters, 3 barriers/K-tile, counted vmcnt(8) once per K-tile.
// 32x32x16 frags: A/B lane row=l&31, k=j*16+(l>>5)*8 -> granule (2j+hi5)^(l&7).
// C/D: col=l&31, row=(r&3)+8*(r>>2)+4*(l>>5)  [m74/m101-verified].
template <int EPI>
__global__ __launch_bounds__(512, 2) void gemm32_kernel(const unsigned short* __restrict__ A,
                                                        const unsigned short* __restrict__ B,
                                                        unsigned short* __restrict__ Obf,
                                                        int ldo, int nbn, int K,
                                                        const float* __restrict__ Xadd,
                                                        float* __restrict__ Ofp) {
  __shared__ unsigned short Lds[2][2][2][8192];  // [op A/B][buf][half][row*64+col]
  const int tid = threadIdx.x;
  const int w = tid >> 6, lane = tid & 63;
  const int wm = w >> 2, wn = w & 3;
  const int l7 = lane & 7, hi5 = lane >> 5;

  // XCD banding: band mt if nbm%8==0 else band nt (nbn%8==0 required then)
  const int nbm = gridDim.x / nbn;
  const int xcd = blockIdx.x & 7;
  const int ib = blockIdx.x >> 3;
  int mt, nt;
  if ((nbm & 7) == 0) {
    const int mtpx = nbm >> 3;
    mt = xcd * mtpx + (ib % mtpx);
    nt = ib / mtpx;
  } else {
    const int ntpx = nbn >> 3;
    nt = xcd * ntpx + (ib % ntpx);
    mt = ib / ntpx;
  }
  const size_t m0 = (size_t)mt * 256, n0 = (size_t)nt * 256;

  // staging source: row (lane>>3), pre-swizzled k-granule (lane&7)^(lane>>3)
  const unsigned short* gA = A + (m0 + (lane >> 3)) * (size_t)K + ((lane & 7) ^ (lane >> 3)) * 8;
  const unsigned short* gB = B + (n0 + (lane >> 3)) * (size_t)K + ((lane & 7) ^ (lane >> 3)) * 8;
  const int wrow = w * 8;

  auto stageA = [&](int b, int h, int kt) {
    const unsigned short* g = gA + (size_t)(h * 128) * K + (size_t)kt * 64;
    GLDS(g + (size_t)wrow * K,        &Lds[0][b][h][wrow * 64]);
    GLDS(g + (size_t)(64 + wrow) * K, &Lds[0][b][h][(64 + wrow) * 64]);
  };
  auto stageB = [&](int b, int h, int kt) {
    const unsigned short* g = gB + (size_t)(h * 128) * K + (size_t)kt * 64;
    GLDS(g + (size_t)wrow * K,        &Lds[1][b][h][wrow * 64]);
    GLDS(g + (size_t)(64 + wrow) * K, &Lds[1][b][h][(64 + wrow) * 64]);
  };

  f32x16 acc32[4][2];
#pragma unroll
  for (int i = 0; i < 4; ++i)
#pragma unroll
    for (int j = 0; j < 2; ++j)
#pragma unroll
      for (int e = 0; e < 16; ++e) acc32[i][j][e] = 0.f;

  const int KT = K >> 6;
  const int rowA = (lane & 31) * 64;       // row-within-32-tile * 64 elems
  const int boff = (wn & 1) * 4096;        // 64 rows into the B half
  // swizzled 8-elem slot for k-slice j: ((2j+hi5)^(l&7))*8
  int slotj[4];
#pragma unroll
  for (int j = 0; j < 4; ++j) slotj[j] = ((((j << 1) | hi5) ^ l7) << 3);

  bf16x8 aF[4][4], bF[2][4];

  // ---- prologue: stage t0 fully + t1 fully; vmcnt(8) -> t0 landed ----
  stageA(0, 0, 0); stageA(0, 1, 0); stageB(0, 0, 0); stageB(0, 1, 0);
  if (KT > 1) {
    stageB(1, 0, 1); stageB(1, 1, 1); stageA(1, 0, 1); stageA(1, 1, 1);
    VMC(8);
  } else {
    VMC(0);
  }
  BARF();

  int bb = 0;
  for (int t = 0; t < KT; ++t, bb ^= 1) {
    const unsigned short* Ab = &Lds[0][bb][wm][0];
    const unsigned short* Bb = &Lds[1][bb][wn >> 1][boff];

    // ---- reads: aF[0..1] (8) + bF[0..1] (8) ----
#pragma unroll
    for (int j = 0; j < 4; ++j) {
      aF[0][j] = *(const bf16x8*)&Ab[rowA + slotj[j]];
      aF[1][j] = *(const bf16x8*)&Ab[2048 + rowA + slotj[j]];
      bF[0][j] = *(const bf16x8*)&Bb[rowA + slotj[j]];
      bF[1][j] = *(const bf16x8*)&Bb[2048 + rowA + slotj[j]];
    }

    // ---- q0: mi 0-1 x ni 0 ----
    __builtin_amdgcn_s_setprio(1);
#pragma unroll
    for (int mi = 0; mi < 2; ++mi)
#pragma unroll
      for (int j = 0; j < 4; ++j)
        acc32[mi][0] = __builtin_amdgcn_mfma_f32_32x32x16_bf16(aF[mi][j], bF[0][j], acc32[mi][0], 0, 0, 0);
    __builtin_amdgcn_s_setprio(0);

    // ---- reads: aF[2..3] (8) ----
#pragma unroll
    for (int j = 0; j < 4; ++j) {
      aF[2][j] = *(const bf16x8*)&Ab[4096 + rowA + slotj[j]];
      aF[3][j] = *(const bf16x8*)&Ab[6144 + rowA + slotj[j]];
    }

    // ---- q1: mi 0-1 x ni 1 ----
    __builtin_amdgcn_s_setprio(1);
#pragma unroll
    for (int mi = 0; mi < 2; ++mi)
#pragma unroll
      for (int j = 0; j < 4; ++j)
        acc32[mi][1] = __builtin_amdgcn_mfma_f32_32x32x16_bf16(aF[mi][j], bF[1][j], acc32[mi][1], 0, 0, 0);
    __builtin_amdgcn_s_setprio(0);
    BARF();  // all waves' B LDS reads retired -> B region stageable

    if (t + 2 < KT) { stageB(bb, 0, t + 2); stageB(bb, 1, t + 2); }

    // ---- q2: mi 2-3 x ni 1 ----
    __builtin_amdgcn_s_setprio(1);
#pragma unroll
    for (int mi = 2; mi < 4; ++mi)
#pragma unroll
      for (int j = 0; j < 4; ++j)
        acc32[mi][1] = __builtin_amdgcn_mfma_f32_32x32x16_bf16(aF[mi][j], bF[1][j], acc32[mi][1], 0, 0, 0);
    __builtin_amdgcn_s_setprio(0);
    BARF();  // all waves' A LDS reads retired -> A region stageable

    if (t + 2 < KT) { stageA(bb, 0, t + 2); stageA(bb, 1, t + 2); }

    // ---- q3: mi 2-3 x ni 0 ----
    __builtin_amdgcn_s_setprio(1);
#pragma unroll
    for (int mi = 2; mi < 4; ++mi)
#pragma unroll
      for (int j = 0; j < 4; ++j)
        acc32[mi][0] = __builtin_amdgcn_mfma_f32_32x32x16_bf16(aF[mi][j], bF[0][j], acc32[mi][0], 0, 0, 0);
    __builtin_amdgcn_s_setprio(0);

    if (t + 2 < KT) {
      VMC(8);
    } else {
      VMC(0);
    }
    BARF();
  }

  if (EPI == 0) {
    // wave-private LDS repack -> coalesced u16x8 stores
    unsigned short* cw = &Lds[0][0][0][0] + (size_t)w * 8192;  // [128][64]
#pragma unroll
    for (int mi = 0; mi < 4; ++mi)
#pragma unroll
      for (int ni = 0; ni < 2; ++ni)
#pragma unroll
        for (int r = 0; r < 16; ++r) {
          int rowl = mi * 32 + (r & 3) + ((r >> 2) << 3) + (hi5 << 2);
          cw[rowl * 64 + ni * 32 + (lane & 31)] = f2bf(acc32[mi][ni][r]);
        }
    asm volatile("s_waitcnt lgkmcnt(0)" ::: "memory");
    const size_t gr0 = m0 + wm * 128;
    const size_t gc0 = n0 + wn * 64;
#pragma unroll
    for (int it = 0; it < 16; ++it) {
      int idx = it * 64 + lane;
      int rr = idx >> 3, c8 = (idx & 7) * 8;
      *(u16x8*)&Obf[(gr0 + rr) * (size_t)ldo + gc0 + c8] = *(const u16x8*)&cw[rr * 64 + c8];
    }
  } else {
    // direct coalesced f32 store: C'[row=c][col=t] = acc + Xadd, row stride T_TOK
    const size_t cbase = m0 + wm * 128;
    const size_t tbase = n0 + wn * 64 + (lane & 31);
#pragma unroll
    for (int mi = 0; mi < 4; ++mi)
#pragma unroll
      for (int ni = 0; ni < 2; ++ni)
#pragma unroll
      for (int r = 0; r < 16; ++r) {
        size_t c = cbase + mi * 32 + (r & 3) + ((r >> 2) << 3) + (hi5 << 2);
        size_t o = c * T_TOK + tbase + ni * 32;
        Ofp[o] = acc32[mi][ni][r] + Xadd[o];
      }
  }
}

// ---------------- MFMA windowed attention with RoPE ----------------
__global__ __launch_bounds__(256) void attn_kernel(const unsigned short* __restrict__ qkv,
                                                   const float* __restrict__ ropeT,
                                                   unsigned short* __restrict__ aout) {
  __shared__ unsigned short Vt[4][64][32];
  const int tid = threadIdx.x;
  const int wv = tid >> 6;
  const int lane = tid & 63;
  const int m = lane & 31;
  const int hi = lane >> 5;
  const int gw = blockIdx.x * 4 + wv;
  const int w = gw >> 4, h = gw & 15;
  const size_t rowbase = ((size_t)(w * 32 + m)) * 3072 + (size_t)h * 64;
  const unsigned short* qp = qkv + rowbase;

  u16x8 qv[4], kv[4], vv[4];
#pragma unroll
  for (int s = 0; s < 4; ++s) {
    int off = s * 16 + hi * 8;
    qv[s] = *(const u16x8*)(qp + off);
    kv[s] = *(const u16x8*)(qp + 1024 + off);
    vv[s] = *(const u16x8*)(qp + 2048 + off);
  }

#pragma unroll
  for (int s = 0; s < 4; ++s)
#pragma unroll
    for (int j = 0; j < 8; ++j) {
      int d = s * 16 + hi * 8 + j;
      int slot = (((m >> 3) ^ (d ^ (d >> 2))) & 3) * 8 + (m & 7);
      Vt[wv][d][slot] = vv[s][j];
    }

  f32x4 ct[2][4];
  const float* tp = ropeT + (size_t)(m * 32 + hi * 8) * 2;
#pragma unroll
  for (int kp = 0; kp < 2; ++kp)
#pragma unroll
    for (int q = 0; q < 4; ++q)
      ct[kp][q] = *(const f32x4*)(tp + kp * 32 + q * 4);

  union FU { unsigned u[4]; bf16x8 v; };
  bf16x8 qfr[4], kfr[4];
#pragma unroll
  for (int ks = 0; ks < 4; ++ks) {
    const int kp = ks & 1;
    FU fq, fk;
#pragma unroll
    for (int jp = 0; jp < 4; ++jp) {
      float c0 = ct[kp][jp][0], s0 = ct[kp][jp][1];
      float c1 = ct[kp][jp][2], s1 = ct[kp][jp][3];
      float q0 = bf2f(qv[ks][2 * jp]), q1 = bf2f(qv[ks][2 * jp + 1]);
      float k0 = bf2f(kv[ks][2 * jp]), k1 = bf2f(kv[ks][2 * jp + 1]);
      float rq0, rq1, rk0, rk1;
      if (ks < 2) {
        rq0 = -bf2f(qv[ks + 2][2 * jp]); rq1 = -bf2f(qv[ks + 2][2 * jp + 1]);
        rk0 = -bf2f(kv[ks + 2][2 * jp]); rk1 = -bf2f(kv[ks + 2][2 * jp + 1]);
      } else {
        rq0 = bf2f(qv[ks - 2][2 * jp]); rq1 = bf2f(qv[ks - 2][2 * jp + 1]);
        rk0 = bf2f(kv[ks - 2][2 * jp]); rk1 = bf2f(kv[ks - 2][2 * jp + 1]);
      }
      fq.u[jp] = pk2(q0 * c0 + rq0 * s0, q1 * c1 + rq1 * s1);
      fk.u[jp] = pk2(k0 * c0 + rk0 * s0, k1 * c1 + rk1 * s1);
    }
    qfr[ks] = fq.v; kfr[ks] = fk.v;
  }

  f32x16 accS;
#pragma unroll
  for (int i = 0; i < 16; ++i) accS[i] = 0.f;
#pragma unroll
  for (int ks = 0; ks < 4; ++ks)
    accS = __builtin_amdgcn_mfma_f32_32x32x16_bf16(kfr[ks], qfr[ks], accS, 0, 0, 0);

  float p[16];
  float mx = -1e30f;
#pragma unroll
  for (int r = 0; r < 16; ++r) { p[r] = accS[r] * 0.125f; mx = fmaxf(mx, p[r]); }
  mx = fmaxf(mx, __shfl_xor(mx, 32, 64));
  float sum = 0.f;
#pragma unroll
  for (int r = 0; r < 16; ++r) { p[r] = __expf(p[r] - mx); sum += p[r]; }
  sum += __shfl_xor(sum, 32, 64);
  const float inv = 1.f / sum;
#pragma unroll
  for (int r = 0; r < 16; ++r) p[r] *= inv;

  bf16x8 pfr[2];
  {
    FU f0, f1;
    unsigned a0 = hi ? pk2(p[0], p[1]) : pk2(p[4], p[5]);
    unsigned a1 = hi ? pk2(p[2], p[3]) : pk2(p[6], p[7]);
    unsigned b0 = (unsigned)__shfl_xor((int)a0, 32, 64);
    unsigned b1 = (unsigned)__shfl_xor((int)a1, 32, 64);
    if (hi) { f0.u[0] = b0; f0.u[1] = b1; f0.u[2] = pk2(p[4], p[5]); f0.u[3] = pk2(p[6], p[7]); }
    else    { f0.u[0] = pk2(p[0], p[1]); f0.u[1] = pk2(p[2], p[3]); f0.u[2] = b0; f0.u[3] = b1; }
    unsigned a2 = hi ? pk2(p[8], p[9])   : pk2(p[12], p[13]);
    unsigned a3 = hi ? pk2(p[10], p[11]) : pk2(p[14], p[15]);
    unsigned b2 = (unsigned)__shfl_xor((int)a2, 32, 64);
    unsigned b3 = (unsigned)__shfl_xor((int)a3, 32, 64);
    if (hi) { f1.u[0] = b2; f1.u[1] = b3; f1.u[2] = pk2(p[12], p[13]); f1.u[3] = pk2(p[14], p[15]); }
    else    { f1.u[0] = pk2(p[8], p[9]); f1.u[1] = pk2(p[10], p[11]); f1.u[2] = b2; f1.u[3] = b3; }
    pfr[0] = f0.v; pfr[1] = f1.v;
  }

  f32x16 accO[2];
#pragma unroll
  for (int i = 0; i < 16; ++i) { accO[0][i] = 0.f; accO[1][i] = 0.f; }
  const int dl = lane & 31;
#pragma unroll
  for (int dh = 0; dh < 2; ++dh) {
    int d = dh * 32 + dl;
    int sx = (d ^ (d >> 2)) & 3;
#pragma unroll
    for (int ks = 0; ks < 2; ++ks) {
      bf16x8 vf = *(const bf16x8*)&Vt[wv][d][(((2 * ks + hi) ^ sx) & 3) * 8];
      accO[dh] = __builtin_amdgcn_mfma_f32_32x32x16_bf16(pfr[ks], vf, accO[dh], 0, 0, 0);
    }
  }

#pragma unroll
  for (int r = 0; r < 16; ++r) {
    int n = (r & 3) + 8 * (r >> 2) + 4 * hi;
    size_t o = (size_t)(w * 32 + n) * 1024 + h * 64 + dl;
    aout[o] = f2bf(accO[0][r]);
    aout[o + 32] = f2bf(accO[1][r]);
  }
}

extern "C" void kernel_launch(void* const* d_in, const int* in_sizes, int n_in,
                              void* d_out, int out_size, void* d_ws, size_t ws_size,
                              hipStream_t stream) {
  const float* x     = (const float*)d_in[0];
  const float* w_qkv = (const float*)d_in[1];
  const float* w_out = (const float*)d_in[2];
  const float* gamma = (const float*)d_in[3];
  const float* beta  = (const float*)d_in[4];

  char* ws = (char*)d_ws;
  unsigned short* wqkv_bf = (unsigned short*)(ws);                       // 6,291,456 B
  unsigned short* wout_bf = (unsigned short*)(ws + 6291456);             // 2,097,152 B
  float* mu    = (float*)(ws + 8388608);                                 // 65,536 B
  float* rstd  = (float*)(ws + 8454144);                                 // 65,536 B
  float* ropeT = (float*)(ws + 8519680);                                 // 8,192 B
  unsigned short* normed = (unsigned short*)(ws + 8527872);              // 33,554,432 B
  unsigned short* qkv    = (unsigned short*)(ws + 42082304);             // 100,663,296 B
  unsigned short* aout   = normed;  // reuse: normed dead after GEMM1

  cvt_kernel<<<3072, 256, 0, stream>>>(w_qkv, wqkv_bf, 3072 * 1024 / 4);
  cvt_kernel<<<1024, 256, 0, stream>>>(w_out, wout_bf, 1024 * 1024 / 4);
  rope_tab_kernel<<<4, 256, 0, stream>>>(ropeT);
  ln_stats_kernel<<<256, 256, 0, stream>>>(x, mu, rstd);
  ln_tr_kernel<<<4096, 256, 0, stream>>>(x, mu, rstd, gamma, beta, normed);
  // GEMM1: (T x 3C) = normed (16384x1024) @ wqkv^T -> grid 64*12 = 768
  gemm32_kernel<0><<<768, 512, 0, stream>>>(normed, wqkv_bf, qkv, 3072, 12, 1024,
                                            nullptr, nullptr);
  attn_kernel<<<2048, 256, 0, stream>>>(qkv, ropeT, aout);
  // GEMM2': d_out (C x T) = w_out (1024x1024) @ aout^T (+ x), grid 4*64 = 256
  gemm32_kernel<1><<<256, 512, 0, stream>>>(wout_bf, aout, nullptr, 0, 64, 1024,
                                            x, (float*)d_out);
}

// Round 10
// 211.345 us; speedup vs baseline: 1.1568x; 1.1568x over previous
//
#include <hip/hip_runtime.h>

#define T_TOK 16384
#define C_DIM 1024

typedef float f32x4 __attribute__((ext_vector_type(4)));
typedef float f32x16 __attribute__((ext_vector_type(16)));
typedef __bf16 bf16x8 __attribute__((ext_vector_type(8)));
typedef unsigned short u16x8 __attribute__((ext_vector_type(8)));
typedef unsigned short u16x4 __attribute__((ext_vector_type(4)));

__device__ __forceinline__ unsigned short f2bf(float f) {
  union { float f; unsigned u; } v; v.f = f;
  unsigned r = v.u + 0x7fffu + ((v.u >> 16) & 1u);
  return (unsigned short)(r >> 16);
}
__device__ __forceinline__ float bf2f(unsigned short h) {
  union { unsigned u; float f; } v; v.u = ((unsigned)h) << 16;
  return v.f;
}
__device__ __forceinline__ unsigned pk2(float a, float b) {
  return (unsigned)f2bf(a) | ((unsigned)f2bf(b) << 16);
}

// ---------------- f32 -> bf16 weight conversion ----------------
__global__ __launch_bounds__(256) void cvt_kernel(const float* __restrict__ in,
                                                  unsigned short* __restrict__ out, int n4) {
  int i = blockIdx.x * 256 + threadIdx.x;
  if (i >= n4) return;
  f32x4 v = *(const f32x4*)(in + (size_t)i * 4);
  u16x4 o;
#pragma unroll
  for (int j = 0; j < 4; ++j) o[j] = f2bf(v[j]);
  *(u16x4*)(out + (size_t)i * 4) = o;
}

// ---------------- RoPE table: [32 pos][32 dmod] float2 (cos,sin) ----------------
__global__ __launch_bounds__(256) void rope_tab_kernel(float* __restrict__ tab) {
  int idx = blockIdx.x * 256 + threadIdx.x;
  if (idx >= 1024) return;
  int mm = idx >> 5, d = idx & 31;
  float invf = powf(10000.f, -(float)d * (1.f / 32.f));
  float ang = (float)mm * invf;
  float s, c;
  sincosf(ang, &s, &c);
  tab[idx * 2] = c;
  tab[idx * 2 + 1] = s;
}

// ---------------- LayerNorm stats: mean/rstd per token ----------------
__global__ __launch_bounds__(256) void ln_stats_kernel(const float* __restrict__ x,
                                                       float* __restrict__ mu,
                                                       float* __restrict__ rstd) {
  __shared__ float s1[4][64];
  __shared__ float s2[4][64];
  const int tid = threadIdx.x;
  const int lt = tid & 63, cq = tid >> 6;
  const int t = blockIdx.x * 64 + lt;
  float s = 0.f, ss = 0.f;
  const float* p = x + (size_t)cq * 256 * T_TOK + t;
  for (int c = 0; c < 256; ++c) {
    float v = p[(size_t)c * T_TOK];
    s += v; ss += v * v;
  }
  s1[cq][lt] = s; s2[cq][lt] = ss;
  __syncthreads();
  if (tid < 64) {
    float S  = s1[0][tid] + s1[1][tid] + s1[2][tid] + s1[3][tid];
    float SS = s2[0][tid] + s2[1][tid] + s2[2][tid] + s2[3][tid];
    float m = S * (1.f / 1024.f);
    float var = SS * (1.f / 1024.f) - m * m;
    mu[blockIdx.x * 64 + tid] = m;
    rstd[blockIdx.x * 64 + tid] = rsqrtf(var + 1e-5f);
  }
}

// ---------------- LN apply + transpose: x (C,T) -> normed (T,C) bf16 ----------------
__global__ __launch_bounds__(256) void ln_tr_kernel(const float* __restrict__ x,
                                                    const float* __restrict__ mu,
                                                    const float* __restrict__ rstd,
                                                    const float* __restrict__ gamma,
                                                    const float* __restrict__ beta,
                                                    unsigned short* __restrict__ normed) {
  __shared__ float tile[64][65];
  __shared__ float gs[64], bs[64], ms[64], rs[64];
  const int tid = threadIdx.x;
  const int bt = blockIdx.x & 255;
  const int bc = blockIdx.x >> 8;
  const int t0 = bt * 64, c0 = bc * 64;
  if (tid < 64) {
    gs[tid] = gamma[c0 + tid];
    bs[tid] = beta[c0 + tid];
    ms[tid] = mu[t0 + tid];
    rs[tid] = rstd[t0 + tid];
  }
  const int lc = tid >> 4;
  const int lt4 = (tid & 15) * 4;
#pragma unroll
  for (int r = 0; r < 4; ++r) {
    int c = r * 16 + lc;
    f32x4 v = *(const f32x4*)&x[(size_t)(c0 + c) * T_TOK + t0 + lt4];
    tile[c][lt4 + 0] = v[0]; tile[c][lt4 + 1] = v[1];
    tile[c][lt4 + 2] = v[2]; tile[c][lt4 + 3] = v[3];
  }
  __syncthreads();
#pragma unroll
  for (int r = 0; r < 2; ++r) {
    int idx = r * 256 + tid;
    int t = idx >> 3;
    int c8 = (idx & 7) * 8;
    float m = ms[t], rr = rs[t];
    u16x8 o;
#pragma unroll
    for (int j = 0; j < 8; ++j) {
      float v = tile[c8 + j][t];
      v = (v - m) * rr * gs[c8 + j] + bs[c8 + j];
      o[j] = f2bf(v);
    }
    *(u16x8*)&normed[(size_t)(t0 + t) * C_DIM + c0 + c8] = o;
  }
}

#define GLDS(gp, lp) \
  __builtin_amdgcn_global_load_lds((const __attribute__((address_space(1))) void*)(gp), \
                                   (__attribute__((address_space(3))) void*)(lp), 16, 0, 0)

#define BARF() do { __builtin_amdgcn_s_barrier(); asm volatile("" ::: "memory"); } while (0)
#define VMC(n) asm volatile("s_waitcnt vmcnt(" #n ")" ::: "memory")

// ================= 256x256 compiler-pipelined bf16 NT GEMM (16x16x32) =================
// C = A * B^T, A: MxK row-major bf16, B: NxK row-major bf16.
// EPI 0: bf16 out (ld=ldo) via wave-private LDS repack (GEMM1: qkv).
// EPI 1: f32 out C[m][n] -> Ofp[m*T_TOK+n] + Xadd[m*T_TOK+n]  (GEMM2':
//        A=w_out, B=aout -> C' = w_out @ aout^T = d_out layout; 64B-run stores).
// 512 threads = 8 waves (2M x 4N); per-wave C: 128x64; BK=64; LDS 128 KiB dbuf.
// R8 schedule: all quadrant reads up front (aLo/bLo/bHi, aHi after q0), 4 MFMA
// clusters, NO lgkmcnt drains (compiler emits counted waits), 3 barriers/K-tile,
// counted vmcnt(8) once per K-tile. FIFO at vmcnt(8): 16 outstanding, keep 8.
template <int EPI>
__global__ __launch_bounds__(512, 2) void gemm8p_kernel(const unsigned short* __restrict__ A,
                                                        const unsigned short* __restrict__ B,
                                                        unsigned short* __restrict__ Obf,
                                                        int ldo, int nbn, int K,
                                                        const float* __restrict__ Xadd,
                                                        float* __restrict__ Ofp) {
  __shared__ unsigned short Lds[2][2][2][8192];  // [op A/B][buf][half][row*64+col]
  const int tid = threadIdx.x;
  const int w = tid >> 6, lane = tid & 63;
  const int wm = w >> 2, wn = w & 3;

  // XCD banding: band mt if nbm%8==0 else band nt (requires nbn%8==0 then)
  const int nbm = gridDim.x / nbn;
  const int xcd = blockIdx.x & 7;
  const int ib = blockIdx.x >> 3;
  int mt, nt;
  if ((nbm & 7) == 0) {
    const int mtpx = nbm >> 3;
    mt = xcd * mtpx + (ib % mtpx);
    nt = ib / mtpx;
  } else {
    const int ntpx = nbn >> 3;
    nt = xcd * ntpx + (ib % ntpx);
    mt = ib / ntpx;
  }
  const size_t m0 = (size_t)mt * 256, n0 = (size_t)nt * 256;

  // staging source base: row (lane>>3), pre-swizzled k-slot (lane&7)^(lane>>3)
  const unsigned short* gA = A + (m0 + (lane >> 3)) * (size_t)K + ((lane & 7) ^ (lane >> 3)) * 8;
  const unsigned short* gB = B + (n0 + (lane >> 3)) * (size_t)K + ((lane & 7) ^ (lane >> 3)) * 8;
  const int wrow = w * 8;

  auto stageA = [&](int b, int h, int kt) {
    const unsigned short* g = gA + (size_t)(h * 128) * K + (size_t)kt * 64;
    GLDS(g + (size_t)wrow * K,        &Lds[0][b][h][wrow * 64]);
    GLDS(g + (size_t)(64 + wrow) * K, &Lds[0][b][h][(64 + wrow) * 64]);
  };
  auto stageB = [&](int b, int h, int kt) {
    const unsigned short* g = gB + (size_t)(h * 128) * K + (size_t)kt * 64;
    GLDS(g + (size_t)wrow * K,        &Lds[1][b][h][wrow * 64]);
    GLDS(g + (size_t)(64 + wrow) * K, &Lds[1][b][h][(64 + wrow) * 64]);
  };

  f32x4 acc[8][4];
#pragma unroll
  for (int i = 0; i < 8; ++i)
#pragma unroll
    for (int j = 0; j < 4; ++j) acc[i][j] = (f32x4){0.f, 0.f, 0.f, 0.f};

  const int KT = K >> 6;
  const int off_r = (lane & 15) * 64;
  const int slot0 = (((lane >> 4) ^ (lane & 7)) * 8);
  const int slot1 = slot0 ^ 32;
  const int boff = (wn & 1) * 4096;

  bf16x8 aLo[4][2], aHi[4][2], bLo[2][2], bHi[2][2];

  // ---- prologue: stage t0 fully + t1 fully; vmcnt(8) -> t0 landed ----
  stageA(0, 0, 0); stageA(0, 1, 0); stageB(0, 0, 0); stageB(0, 1, 0);
  if (KT > 1) {
    stageB(1, 0, 1); stageB(1, 1, 1); stageA(1, 0, 1); stageA(1, 1, 1);
    VMC(8);
  } else {
    VMC(0);
  }
  BARF();

  int bb = 0;
  for (int t = 0; t < KT; ++t, bb ^= 1) {
    const unsigned short* Ab = &Lds[0][bb][wm][0];
    const unsigned short* Bb = &Lds[1][bb][wn >> 1][boff];

    // ---- issue aLo(8) + bLo(4) + bHi(4) reads; compiler counts the waits ----
#pragma unroll
    for (int mi = 0; mi < 4; ++mi) {
      aLo[mi][0] = *(const bf16x8*)&Ab[mi * 1024 + off_r + slot0];
      aLo[mi][1] = *(const bf16x8*)&Ab[mi * 1024 + off_r + slot1];
    }
#pragma unroll
    for (int ni = 0; ni < 2; ++ni) {
      bLo[ni][0] = *(const bf16x8*)&Bb[ni * 1024 + off_r + slot0];
      bLo[ni][1] = *(const bf16x8*)&Bb[ni * 1024 + off_r + slot1];
      bHi[ni][0] = *(const bf16x8*)&Bb[(ni + 2) * 1024 + off_r + slot0];
      bHi[ni][1] = *(const bf16x8*)&Bb[(ni + 2) * 1024 + off_r + slot1];
    }

    // ---- q0: aLo x bLo (bHi drains underneath) ----
    __builtin_amdgcn_s_setprio(1);
#pragma unroll
    for (int mi = 0; mi < 4; ++mi)
#pragma unroll
      for (int ni = 0; ni < 2; ++ni)
#pragma unroll
        for (int ks = 0; ks < 2; ++ks)
          acc[mi][ni] = __builtin_amdgcn_mfma_f32_16x16x32_bf16(aLo[mi][ks], bLo[ni][ks], acc[mi][ni], 0, 0, 0);
    __builtin_amdgcn_s_setprio(0);

    // ---- issue aHi(8) reads (drain under q1) ----
#pragma unroll
    for (int mi = 0; mi < 4; ++mi) {
      aHi[mi][0] = *(const bf16x8*)&Ab[(mi + 4) * 1024 + off_r + slot0];
      aHi[mi][1] = *(const bf16x8*)&Ab[(mi + 4) * 1024 + off_r + slot1];
    }

    // ---- q1: aLo x bHi ----
    __builtin_amdgcn_s_setprio(1);
#pragma unroll
    for (int mi = 0; mi < 4; ++mi)
#pragma unroll
      for (int ni = 0; ni < 2; ++ni)
#pragma unroll
        for (int ks = 0; ks < 2; ++ks)
          acc[mi][ni + 2] = __builtin_amdgcn_mfma_f32_16x16x32_bf16(aLo[mi][ks], bHi[ni][ks], acc[mi][ni + 2], 0, 0, 0);
    __builtin_amdgcn_s_setprio(0);
    BARF();  // all waves' B reads retired (q0/q1 consumed them) -> B stageable

    if (t + 2 < KT) { stageB(bb, 0, t + 2); stageB(bb, 1, t + 2); }

    // ---- q2: aHi x bHi ----
    __builtin_amdgcn_s_setprio(1);
#pragma unroll
    for (int mi = 0; mi < 4; ++mi)
#pragma unroll
      for (int ni = 0; ni < 2; ++ni)
#pragma unroll
        for (int ks = 0; ks < 2; ++ks)
          acc[mi + 4][ni + 2] = __builtin_amdgcn_mfma_f32_16x16x32_bf16(aHi[mi][ks], bHi[ni][ks], acc[mi + 4][ni + 2], 0, 0, 0);
    __builtin_amdgcn_s_setprio(0);
    BARF();  // all waves' A reads retired -> A stageable

    if (t + 2 < KT) { stageA(bb, 0, t + 2); stageA(bb, 1, t + 2); }

    // ---- q3: aHi x bLo ----
    __builtin_amdgcn_s_setprio(1);
#pragma unroll
    for (int mi = 0; mi < 4; ++mi)
#pragma unroll
      for (int ni = 0; ni < 2; ++ni)
#pragma unroll
        for (int ks = 0; ks < 2; ++ks)
          acc[mi + 4][ni] = __builtin_amdgcn_mfma_f32_16x16x32_bf16(aHi[mi][ks], bLo[ni][ks], acc[mi + 4][ni], 0, 0, 0);
    __builtin_amdgcn_s_setprio(0);

    if (t + 2 < KT) {
      VMC(8);
    } else {
      VMC(0);
    }
    BARF();
  }

  if (EPI == 0) {
    // wave-private LDS repack -> coalesced u16x8 stores (LDS fully dead post-loop)
    unsigned short* cw = &Lds[0][0][0][0] + (size_t)w * 8192;
#pragma unroll
    for (int mi = 0; mi < 8; ++mi)
#pragma unroll
      for (int ni = 0; ni < 4; ++ni)
#pragma unroll
        for (int r = 0; r < 4; ++r)
          cw[(mi * 16 + (lane >> 4) * 4 + r) * 64 + ni * 16 + (lane & 15)] = f2bf(acc[mi][ni][r]);
    const size_t gr0 = m0 + wm * 128;
    const size_t gc0 = n0 + wn * 64;
#pragma unroll
    for (int it = 0; it < 16; ++it) {
      int idx = it * 64 + lane;
      int rr = idx >> 3, c8 = (idx & 7) * 8;
      *(u16x8*)&Obf[(gr0 + rr) * (size_t)ldo + gc0 + c8] = *(const u16x8*)&cw[rr * 64 + c8];
    }
  } else {
    // direct f32 store: C[m][n] = acc + Xadd at m*T_TOK+n.
    // lanes 0-15 of each quad-group cover 16 consecutive n -> 64B runs.
    const size_t mrow0 = m0 + wm * 128 + (lane >> 4) * 4;
    const size_t ncol0 = n0 + wn * 64 + (lane & 15);
#pragma unroll
    for (int mi = 0; mi < 8; ++mi)
#pragma unroll
      for (int ni = 0; ni < 4; ++ni)
#pragma unroll
        for (int r = 0; r < 4; ++r) {
          size_t o = (mrow0 + mi * 16 + r) * T_TOK + ncol0 + ni * 16;
          Ofp[o] = acc[mi][ni][r] + Xadd[o];
        }
  }
}

// ---------------- MFMA windowed attention with RoPE ----------------
__global__ __launch_bounds__(256) void attn_kernel(const unsigned short* __restrict__ qkv,
                                                   const float* __restrict__ ropeT,
                                                   unsigned short* __restrict__ aout) {
  __shared__ unsigned short Vt[4][64][32];
  const int tid = threadIdx.x;
  const int wv = tid >> 6;
  const int lane = tid & 63;
  const int m = lane & 31;
  const int hi = lane >> 5;
  const int gw = blockIdx.x * 4 + wv;
  const int w = gw >> 4, h = gw & 15;
  const size_t rowbase = ((size_t)(w * 32 + m)) * 3072 + (size_t)h * 64;
  const unsigned short* qp = qkv + rowbase;

  u16x8 qv[4], kv[4], vv[4];
#pragma unroll
  for (int s = 0; s < 4; ++s) {
    int off = s * 16 + hi * 8;
    qv[s] = *(const u16x8*)(qp + off);
    kv[s] = *(const u16x8*)(qp + 1024 + off);
    vv[s] = *(const u16x8*)(qp + 2048 + off);
  }

#pragma unroll
  for (int s = 0; s < 4; ++s)
#pragma unroll
    for (int j = 0; j < 8; ++j) {
      int d = s * 16 + hi * 8 + j;
      int slot = (((m >> 3) ^ (d ^ (d >> 2))) & 3) * 8 + (m & 7);
      Vt[wv][d][slot] = vv[s][j];
    }

  f32x4 ct[2][4];
  const float* tp = ropeT + (size_t)(m * 32 + hi * 8) * 2;
#pragma unroll
  for (int kp = 0; kp < 2; ++kp)
#pragma unroll
    for (int q = 0; q < 4; ++q)
      ct[kp][q] = *(const f32x4*)(tp + kp * 32 + q * 4);

  union FU { unsigned u[4]; bf16x8 v; };
  bf16x8 qfr[4], kfr[4];
#pragma unroll
  for (int ks = 0; ks < 4; ++ks) {
    const int kp = ks & 1;
    FU fq, fk;
#pragma unroll
    for (int jp = 0; jp < 4; ++jp) {
      float c0 = ct[kp][jp][0], s0 = ct[kp][jp][1];
      float c1 = ct[kp][jp][2], s1 = ct[kp][jp][3];
      float q0 = bf2f(qv[ks][2 * jp]), q1 = bf2f(qv[ks][2 * jp + 1]);
      float k0 = bf2f(kv[ks][2 * jp]), k1 = bf2f(kv[ks][2 * jp + 1]);
      float rq0, rq1, rk0, rk1;
      if (ks < 2) {
        rq0 = -bf2f(qv[ks + 2][2 * jp]); rq1 = -bf2f(qv[ks + 2][2 * jp + 1]);
        rk0 = -bf2f(kv[ks + 2][2 * jp]); rk1 = -bf2f(kv[ks + 2][2 * jp + 1]);
      } else {
        rq0 = bf2f(qv[ks - 2][2 * jp]); rq1 = bf2f(qv[ks - 2][2 * jp + 1]);
        rk0 = bf2f(kv[ks - 2][2 * jp]); rk1 = bf2f(kv[ks - 2][2 * jp + 1]);
      }
      fq.u[jp] = pk2(q0 * c0 + rq0 * s0, q1 * c1 + rq1 * s1);
      fk.u[jp] = pk2(k0 * c0 + rk0 * s0, k1 * c1 + rk1 * s1);
    }
    qfr[ks] = fq.v; kfr[ks] = fk.v;
  }

  f32x16 accS;
#pragma unroll
  for (int i = 0; i < 16; ++i) accS[i] = 0.f;
#pragma unroll
  for (int ks = 0; ks < 4; ++ks)
    accS = __builtin_amdgcn_mfma_f32_32x32x16_bf16(kfr[ks], qfr[ks], accS, 0, 0, 0);

  float p[16];
  float mx = -1e30f;
#pragma unroll
  for (int r = 0; r < 16; ++r) { p[r] = accS[r] * 0.125f; mx = fmaxf(mx, p[r]); }
  mx = fmaxf(mx, __shfl_xor(mx, 32, 64));
  float sum = 0.f;
#pragma unroll
  for (int r = 0; r < 16; ++r) { p[r] = __expf(p[r] - mx); sum += p[r]; }
  sum += __shfl_xor(sum, 32, 64);
  const float inv = 1.f / sum;
#pragma unroll
  for (int r = 0; r < 16; ++r) p[r] *= inv;

  bf16x8 pfr[2];
  {
    FU f0, f1;
    unsigned a0 = hi ? pk2(p[0], p[1]) : pk2(p[4], p[5]);
    unsigned a1 = hi ? pk2(p[2], p[3]) : pk2(p[6], p[7]);
    unsigned b0 = (unsigned)__shfl_xor((int)a0, 32, 64);
    unsigned b1 = (unsigned)__shfl_xor((int)a1, 32, 64);
    if (hi) { f0.u[0] = b0; f0.u[1] = b1; f0.u[2] = pk2(p[4], p[5]); f0.u[3] = pk2(p[6], p[7]); }
    else    { f0.u[0] = pk2(p[0], p[1]); f0.u[1] = pk2(p[2], p[3]); f0.u[2] = b0; f0.u[3] = b1; }
    unsigned a2 = hi ? pk2(p[8], p[9])   : pk2(p[12], p[13]);
    unsigned a3 = hi ? pk2(p[10], p[11]) : pk2(p[14], p[15]);
    unsigned b2 = (unsigned)__shfl_xor((int)a2, 32, 64);
    unsigned b3 = (unsigned)__shfl_xor((int)a3, 32, 64);
    if (hi) { f1.u[0] = b2; f1.u[1] = b3; f1.u[2] = pk2(p[12], p[13]); f1.u[3] = pk2(p[14], p[15]); }
    else    { f1.u[0] = pk2(p[8], p[9]); f1.u[1] = pk2(p[10], p[11]); f1.u[2] = b2; f1.u[3] = b3; }
    pfr[0] = f0.v; pfr[1] = f1.v;
  }

  f32x16 accO[2];
#pragma unroll
  for (int i = 0; i < 16; ++i) { accO[0][i] = 0.f; accO[1][i] = 0.f; }
  const int dl = lane & 31;
#pragma unroll
  for (int dh = 0; dh < 2; ++dh) {
    int d = dh * 32 + dl;
    int sx = (d ^ (d >> 2)) & 3;
#pragma unroll
    for (int ks = 0; ks < 2; ++ks) {
      bf16x8 vf = *(const bf16x8*)&Vt[wv][d][(((2 * ks + hi) ^ sx) & 3) * 8];
      accO[dh] = __builtin_amdgcn_mfma_f32_32x32x16_bf16(pfr[ks], vf, accO[dh], 0, 0, 0);
    }
  }

#pragma unroll
  for (int r = 0; r < 16; ++r) {
    int n = (r & 3) + 8 * (r >> 2) + 4 * hi;
    size_t o = (size_t)(w * 32 + n) * 1024 + h * 64 + dl;
    aout[o] = f2bf(accO[0][r]);
    aout[o + 32] = f2bf(accO[1][r]);
  }
}

extern "C" void kernel_launch(void* const* d_in, const int* in_sizes, int n_in,
                              void* d_out, int out_size, void* d_ws, size_t ws_size,
                              hipStream_t stream) {
  const float* x     = (const float*)d_in[0];
  const float* w_qkv = (const float*)d_in[1];
  const float* w_out = (const float*)d_in[2];
  const float* gamma = (const float*)d_in[3];
  const float* beta  = (const float*)d_in[4];

  char* ws = (char*)d_ws;
  unsigned short* wqkv_bf = (unsigned short*)(ws);                       // 6,291,456 B
  unsigned short* wout_bf = (unsigned short*)(ws + 6291456);             // 2,097,152 B
  float* mu    = (float*)(ws + 8388608);                                 // 65,536 B
  float* rstd  = (float*)(ws + 8454144);                                 // 65,536 B
  float* ropeT = (float*)(ws + 8519680);                                 // 8,192 B
  unsigned short* normed = (unsigned short*)(ws + 8527872);              // 33,554,432 B
  unsigned short* qkv    = (unsigned short*)(ws + 42082304);             // 100,663,296 B
  unsigned short* aout   = normed;  // reuse: normed dead after GEMM1

  cvt_kernel<<<3072, 256, 0, stream>>>(w_qkv, wqkv_bf, 3072 * 1024 / 4);
  cvt_kernel<<<1024, 256, 0, stream>>>(w_out, wout_bf, 1024 * 1024 / 4);
  rope_tab_kernel<<<4, 256, 0, stream>>>(ropeT);
  ln_stats_kernel<<<256, 256, 0, stream>>>(x, mu, rstd);
  ln_tr_kernel<<<4096, 256, 0, stream>>>(x, mu, rstd, gamma, beta, normed);
  // GEMM1: qkv (16384x3072) = normed @ wqkv^T -> grid 64*12 = 768
  gemm8p_kernel<0><<<768, 512, 0, stream>>>(normed, wqkv_bf, qkv, 3072, 12, 1024,
                                            nullptr, nullptr);
  attn_kernel<<<2048, 256, 0, stream>>>(qkv, ropeT, aout);
  // GEMM2': d_out (1024x16384) = w_out @ aout^T + x -> grid 4*64 = 256
  gemm8p_kernel<1><<<256, 512, 0, stream>>>(wout_bf, aout, nullptr, 0, 64, 1024,
                                            x, (float*)d_out);
}

// Round 11
// 205.786 us; speedup vs baseline: 1.1881x; 1.0270x over previous
//
#include <hip/hip_runtime.h>

#define T_TOK 16384
#define C_DIM 1024

typedef float f32x4 __attribute__((ext_vector_type(4)));
typedef float f32x16 __attribute__((ext_vector_type(16)));
typedef __bf16 bf16x8 __attribute__((ext_vector_type(8)));
typedef unsigned short u16x8 __attribute__((ext_vector_type(8)));
typedef unsigned short u16x4 __attribute__((ext_vector_type(4)));

__device__ __forceinline__ unsigned short f2bf(float f) {
  union { float f; unsigned u; } v; v.f = f;
  unsigned r = v.u + 0x7fffu + ((v.u >> 16) & 1u);
  return (unsigned short)(r >> 16);
}
__device__ __forceinline__ float bf2f(unsigned short h) {
  union { unsigned u; float f; } v; v.u = ((unsigned)h) << 16;
  return v.f;
}
__device__ __forceinline__ unsigned pk2(float a, float b) {
  return (unsigned)f2bf(a) | ((unsigned)f2bf(b) << 16);
}

// ---------------- f32 -> bf16 weight conversion ----------------
__global__ __launch_bounds__(256) void cvt_kernel(const float* __restrict__ in,
                                                  unsigned short* __restrict__ out, int n4) {
  int i = blockIdx.x * 256 + threadIdx.x;
  if (i >= n4) return;
  f32x4 v = *(const f32x4*)(in + (size_t)i * 4);
  u16x4 o;
#pragma unroll
  for (int j = 0; j < 4; ++j) o[j] = f2bf(v[j]);
  *(u16x4*)(out + (size_t)i * 4) = o;
}

// ---------------- RoPE table: [32 pos][32 dmod] float2 (cos,sin) ----------------
__global__ __launch_bounds__(256) void rope_tab_kernel(float* __restrict__ tab) {
  int idx = blockIdx.x * 256 + threadIdx.x;
  if (idx >= 1024) return;
  int mm = idx >> 5, d = idx & 31;
  float invf = powf(10000.f, -(float)d * (1.f / 32.f));
  float ang = (float)mm * invf;
  float s, c;
  sincosf(ang, &s, &c);
  tab[idx * 2] = c;
  tab[idx * 2 + 1] = s;
}

// ---------------- LayerNorm stats: mean/rstd per token ----------------
__global__ __launch_bounds__(256) void ln_stats_kernel(const float* __restrict__ x,
                                                       float* __restrict__ mu,
                                                       float* __restrict__ rstd) {
  __shared__ float s1[4][64];
  __shared__ float s2[4][64];
  const int tid = threadIdx.x;
  const int lt = tid & 63, cq = tid >> 6;
  const int t = blockIdx.x * 64 + lt;
  float s = 0.f, ss = 0.f;
  const float* p = x + (size_t)cq * 256 * T_TOK + t;
  for (int c = 0; c < 256; ++c) {
    float v = p[(size_t)c * T_TOK];
    s += v; ss += v * v;
  }
  s1[cq][lt] = s; s2[cq][lt] = ss;
  __syncthreads();
  if (tid < 64) {
    float S  = s1[0][tid] + s1[1][tid] + s1[2][tid] + s1[3][tid];
    float SS = s2[0][tid] + s2[1][tid] + s2[2][tid] + s2[3][tid];
    float m = S * (1.f / 1024.f);
    float var = SS * (1.f / 1024.f) - m * m;
    mu[blockIdx.x * 64 + tid] = m;
    rstd[blockIdx.x * 64 + tid] = rsqrtf(var + 1e-5f);
  }
}

// ---------------- LN apply + transpose: x (C,T) -> normed (T,C) bf16 ----------------
__global__ __launch_bounds__(256) void ln_tr_kernel(const float* __restrict__ x,
                                                    const float* __restrict__ mu,
                                                    const float* __restrict__ rstd,
                                                    const float* __restrict__ gamma,
                                                    const float* __restrict__ beta,
                                                    unsigned short* __restrict__ normed) {
  __shared__ float tile[64][65];
  __shared__ float gs[64], bs[64], ms[64], rs[64];
  const int tid = threadIdx.x;
  const int bt = blockIdx.x & 255;
  const int bc = blockIdx.x >> 8;
  const int t0 = bt * 64, c0 = bc * 64;
  if (tid < 64) {
    gs[tid] = gamma[c0 + tid];
    bs[tid] = beta[c0 + tid];
    ms[tid] = mu[t0 + tid];
    rs[tid] = rstd[t0 + tid];
  }
  const int lc = tid >> 4;
  const int lt4 = (tid & 15) * 4;
#pragma unroll
  for (int r = 0; r < 4; ++r) {
    int c = r * 16 + lc;
    f32x4 v = *(const f32x4*)&x[(size_t)(c0 + c) * T_TOK + t0 + lt4];
    tile[c][lt4 + 0] = v[0]; tile[c][lt4 + 1] = v[1];
    tile[c][lt4 + 2] = v[2]; tile[c][lt4 + 3] = v[3];
  }
  __syncthreads();
#pragma unroll
  for (int r = 0; r < 2; ++r) {
    int idx = r * 256 + tid;
    int t = idx >> 3;
    int c8 = (idx & 7) * 8;
    float m = ms[t], rr = rs[t];
    u16x8 o;
#pragma unroll
    for (int j = 0; j < 8; ++j) {
      float v = tile[c8 + j][t];
      v = (v - m) * rr * gs[c8 + j] + bs[c8 + j];
      o[j] = f2bf(v);
    }
    *(u16x8*)&normed[(size_t)(t0 + t) * C_DIM + c0 + c8] = o;
  }
}

#define GLDS(gp, lp) \
  __builtin_amdgcn_global_load_lds((const __attribute__((address_space(1))) void*)(gp), \
                                   (__attribute__((address_space(3))) void*)(lp), 16, 0, 0)

#define BARF() do { __builtin_amdgcn_s_barrier(); asm volatile("" ::: "memory"); } while (0)
#define VMC(n) asm volatile("s_waitcnt vmcnt(" #n ")" ::: "memory")

// ======== fused QKV-projection + RoPE + windowed attention ========
// One block = (256-token tile tt) x (head h). C = normed_tile @ Bpanel^T where
// Bpanel rows = wqkv rows {h*64..}, {1024+h*64..}, {2048+h*64..} (192 x 1024).
// After the K-loop: repack q,k into LDS [256][136], v into transposed-swizzled
// Vt[8][64][32]; each of the 8 waves runs one 32-token window attention and
// writes aout (T,1024) bf16.  512 thr = 8 waves (4M x 2N); per-wave C 64x96.
// Staging: 7 gload_lds per K-tile (A:4 units of 64 rows, B:3); counted VMC(7).
__global__ __launch_bounds__(512, 2) void qkvattn_kernel(const unsigned short* __restrict__ A,
                                                         const unsigned short* __restrict__ Bq,
                                                         const float* __restrict__ ropeT,
                                                         unsigned short* __restrict__ aout) {
  __shared__ unsigned short arena[57344];  // 114,688 B
  unsigned short* LA = arena;              // [2][256*64]  (32,768 u16)
  unsigned short* LB = arena + 32768;      // [2][192*64]  (24,576 u16)
  unsigned short* QKl = arena;             // epilogue: [256][136] (34,816 u16)
  unsigned short* Vtl = arena + 34816;     // epilogue: [8][64][32] (16,384 u16)

  const int tid = threadIdx.x;
  const int w = tid >> 6, lane = tid & 63;
  const int wm = w >> 1, wn = w & 1;
  const int K = 1024, KT = 16;

  // XCD banding: xcd owns a tt-band of 8; h-major within
  const int xcd = blockIdx.x & 7;
  const int ib = blockIdx.x >> 3;
  const int tt = xcd * 8 + (ib & 7);
  const int h = ib >> 3;
  const size_t m0 = (size_t)tt * 256;

  // staging sources (pre-swizzled k-slot (lane&7)^(lane>>3); LDS row&7 == lane>>3)
  const int preslot = ((lane & 7) ^ (lane >> 3)) * 8;
  const unsigned short* gA = A + (m0 + w * 8 + (lane >> 3)) * (size_t)K + preslot;
  const unsigned short* gB0 = Bq + ((size_t)(0 + h * 64 + w * 8 + (lane >> 3))) * K + preslot;
  const unsigned short* gB1 = Bq + ((size_t)(1024 + h * 64 + w * 8 + (lane >> 3))) * K + preslot;
  const unsigned short* gB2 = Bq + ((size_t)(2048 + h * 64 + w * 8 + (lane >> 3))) * K + preslot;

  auto stage7 = [&](int b, int kt) {
    const size_t k0 = (size_t)kt * 64;
    GLDS(gA + k0,                      LA + b * 16384 + (w * 8) * 64);
    GLDS(gA + (size_t)64 * K + k0,     LA + b * 16384 + (64 + w * 8) * 64);
    GLDS(gA + (size_t)128 * K + k0,    LA + b * 16384 + (128 + w * 8) * 64);
    GLDS(gA + (size_t)192 * K + k0,    LA + b * 16384 + (192 + w * 8) * 64);
    GLDS(gB0 + k0,                     LB + b * 12288 + (w * 8) * 64);
    GLDS(gB1 + k0,                     LB + b * 12288 + (64 + w * 8) * 64);
    GLDS(gB2 + k0,                     LB + b * 12288 + (128 + w * 8) * 64);
  };

  f32x4 acc[4][6];
#pragma unroll
  for (int i = 0; i < 4; ++i)
#pragma unroll
    for (int j = 0; j < 6; ++j) acc[i][j] = (f32x4){0.f, 0.f, 0.f, 0.f};

  const int off_r = (lane & 15) * 64;
  const int slot0 = (((lane >> 4) ^ (lane & 7)) * 8);
  const int slot1 = slot0 ^ 32;

  // ---- prologue: stage t0 + t1; VMC(7) -> t0 landed ----
  stage7(0, 0);
  stage7(1, 1);
  VMC(7);
  BARF();

  int bb = 0;
  for (int t = 0; t < KT; ++t, bb ^= 1) {
    const unsigned short* Ab = LA + bb * 16384 + (wm * 64) * 64;
    const unsigned short* Bb = LB + bb * 12288 + (wn * 96) * 64;

    bf16x8 aF[4][2], bF[6][2];
#pragma unroll
    for (int mi = 0; mi < 4; ++mi) {
      aF[mi][0] = *(const bf16x8*)&Ab[mi * 1024 + off_r + slot0];
      aF[mi][1] = *(const bf16x8*)&Ab[mi * 1024 + off_r + slot1];
    }
#pragma unroll
    for (int ni = 0; ni < 6; ++ni) {
      bF[ni][0] = *(const bf16x8*)&Bb[ni * 1024 + off_r + slot0];
      bF[ni][1] = *(const bf16x8*)&Bb[ni * 1024 + off_r + slot1];
    }

    __builtin_amdgcn_s_setprio(1);
#pragma unroll
    for (int mi = 0; mi < 4; ++mi)
#pragma unroll
      for (int ni = 0; ni < 6; ++ni)
#pragma unroll
        for (int ks = 0; ks < 2; ++ks)
          acc[mi][ni] = __builtin_amdgcn_mfma_f32_16x16x32_bf16(aF[mi][ks], bF[ni][ks], acc[mi][ni], 0, 0, 0);
    __builtin_amdgcn_s_setprio(0);
    BARF();  // all waves' LDS reads retired (MFMA-consumed before barrier)

    if (t + 2 < KT) {
      stage7(bb, t + 2);   // into CURRENT buf: fully dead after barrier
      VMC(7);              // retires tile t+1 (FIFO: t+1's 7 + t+2's 7, keep 7)
    } else {
      VMC(0);
    }
    BARF();
  }

  // ---- epilogue: repack C frags -> QKl [256][136] (q|k), Vtl [8][64][32] (v) ----
  __syncthreads();  // full drain before arena overlay
#pragma unroll
  for (int mi = 0; mi < 4; ++mi)
#pragma unroll
    for (int ni = 0; ni < 6; ++ni) {
      const int j = wn * 96 + ni * 16 + (lane & 15);
#pragma unroll
      for (int r = 0; r < 4; ++r) {
        int tok = wm * 64 + mi * 16 + (lane >> 4) * 4 + r;
        unsigned short bv = f2bf(acc[mi][ni][r]);
        if (wn == 0 || ni < 2) {
          QKl[tok * 136 + j] = bv;
        } else {
          int d = j - 128;
          int mm = tok & 31, win = tok >> 5;
          Vtl[(win * 64 + d) * 32 + ((((mm >> 3) ^ (d ^ (d >> 2))) & 3) * 8 + (mm & 7))] = bv;
        }
      }
    }
  __syncthreads();

  // ---- per-wave window attention (wave w = window w of this tile) ----
  {
    const int m = lane & 31, hi = lane >> 5;
    const unsigned short* qp = QKl + (size_t)(w * 32 + m) * 136;
    u16x8 qv[4], kv[4];
#pragma unroll
    for (int s = 0; s < 4; ++s) {
      int off = s * 16 + hi * 8;
      qv[s] = *(const u16x8*)(qp + off);
      kv[s] = *(const u16x8*)(qp + 64 + off);
    }

    f32x4 ct[2][4];
    const float* tp = ropeT + (size_t)(m * 32 + hi * 8) * 2;
#pragma unroll
    for (int kp = 0; kp < 2; ++kp)
#pragma unroll
      for (int q = 0; q < 4; ++q)
        ct[kp][q] = *(const f32x4*)(tp + kp * 32 + q * 4);

    union FU { unsigned u[4]; bf16x8 v; };
    bf16x8 qfr[4], kfr[4];
#pragma unroll
    for (int ks = 0; ks < 4; ++ks) {
      const int kp = ks & 1;
      FU fq, fk;
#pragma unroll
      for (int jp = 0; jp < 4; ++jp) {
        float c0 = ct[kp][jp][0], s0 = ct[kp][jp][1];
        float c1 = ct[kp][jp][2], s1 = ct[kp][jp][3];
        float q0 = bf2f(qv[ks][2 * jp]), q1 = bf2f(qv[ks][2 * jp + 1]);
        float k0 = bf2f(kv[ks][2 * jp]), k1 = bf2f(kv[ks][2 * jp + 1]);
        float rq0, rq1, rk0, rk1;
        if (ks < 2) {
          rq0 = -bf2f(qv[ks + 2][2 * jp]); rq1 = -bf2f(qv[ks + 2][2 * jp + 1]);
          rk0 = -bf2f(kv[ks + 2][2 * jp]); rk1 = -bf2f(kv[ks + 2][2 * jp + 1]);
        } else {
          rq0 = bf2f(qv[ks - 2][2 * jp]); rq1 = bf2f(qv[ks - 2][2 * jp + 1]);
          rk0 = bf2f(kv[ks - 2][2 * jp]); rk1 = bf2f(kv[ks - 2][2 * jp + 1]);
        }
        fq.u[jp] = pk2(q0 * c0 + rq0 * s0, q1 * c1 + rq1 * s1);
        fk.u[jp] = pk2(k0 * c0 + rk0 * s0, k1 * c1 + rk1 * s1);
      }
      qfr[ks] = fq.v; kfr[ks] = fk.v;
    }

    f32x16 accS;
#pragma unroll
    for (int i = 0; i < 16; ++i) accS[i] = 0.f;
#pragma unroll
    for (int ks = 0; ks < 4; ++ks)
      accS = __builtin_amdgcn_mfma_f32_32x32x16_bf16(kfr[ks], qfr[ks], accS, 0, 0, 0);

    float p[16];
    float mx = -1e30f;
#pragma unroll
    for (int r = 0; r < 16; ++r) { p[r] = accS[r] * 0.125f; mx = fmaxf(mx, p[r]); }
    mx = fmaxf(mx, __shfl_xor(mx, 32, 64));
    float sum = 0.f;
#pragma unroll
    for (int r = 0; r < 16; ++r) { p[r] = __expf(p[r] - mx); sum += p[r]; }
    sum += __shfl_xor(sum, 32, 64);
    const float inv = 1.f / sum;
#pragma unroll
    for (int r = 0; r < 16; ++r) p[r] *= inv;

    bf16x8 pfr[2];
    {
      FU f0, f1;
      unsigned a0 = hi ? pk2(p[0], p[1]) : pk2(p[4], p[5]);
      unsigned a1 = hi ? pk2(p[2], p[3]) : pk2(p[6], p[7]);
      unsigned b0 = (unsigned)__shfl_xor((int)a0, 32, 64);
      unsigned b1 = (unsigned)__shfl_xor((int)a1, 32, 64);
      if (hi) { f0.u[0] = b0; f0.u[1] = b1; f0.u[2] = pk2(p[4], p[5]); f0.u[3] = pk2(p[6], p[7]); }
      else    { f0.u[0] = pk2(p[0], p[1]); f0.u[1] = pk2(p[2], p[3]); f0.u[2] = b0; f0.u[3] = b1; }
      unsigned a2 = hi ? pk2(p[8], p[9])   : pk2(p[12], p[13]);
      unsigned a3 = hi ? pk2(p[10], p[11]) : pk2(p[14], p[15]);
      unsigned b2 = (unsigned)__shfl_xor((int)a2, 32, 64);
      unsigned b3 = (unsigned)__shfl_xor((int)a3, 32, 64);
      if (hi) { f1.u[0] = b2; f1.u[1] = b3; f1.u[2] = pk2(p[12], p[13]); f1.u[3] = pk2(p[14], p[15]); }
      else    { f1.u[0] = pk2(p[8], p[9]); f1.u[1] = pk2(p[10], p[11]); f1.u[2] = b2; f1.u[3] = b3; }
      pfr[0] = f0.v; pfr[1] = f1.v;
    }

    f32x16 accO[2];
#pragma unroll
    for (int i = 0; i < 16; ++i) { accO[0][i] = 0.f; accO[1][i] = 0.f; }
    const int dl = lane & 31;
#pragma unroll
    for (int dh = 0; dh < 2; ++dh) {
      int d = dh * 32 + dl;
      int sx = (d ^ (d >> 2)) & 3;
#pragma unroll
      for (int ks = 0; ks < 2; ++ks) {
        bf16x8 vf = *(const bf16x8*)&Vtl[(w * 64 + d) * 32 + (((2 * ks + hi) ^ sx) & 3) * 8];
        accO[dh] = __builtin_amdgcn_mfma_f32_32x32x16_bf16(pfr[ks], vf, accO[dh], 0, 0, 0);
      }
    }

    const int W = tt * 8 + w;
#pragma unroll
    for (int r = 0; r < 16; ++r) {
      int n = (r & 3) + 8 * (r >> 2) + 4 * hi;
      size_t o = (size_t)(W * 32 + n) * 1024 + h * 64 + dl;
      aout[o] = f2bf(accO[0][r]);
      aout[o + 32] = f2bf(accO[1][r]);
    }
  }
}

// ================= 256x256 compiler-pipelined bf16 NT GEMM (GEMM2') =================
template <int EPI>
__global__ __launch_bounds__(512, 2) void gemm8p_kernel(const unsigned short* __restrict__ A,
                                                        const unsigned short* __restrict__ B,
                                                        unsigned short* __restrict__ Obf,
                                                        int ldo, int nbn, int K,
                                                        const float* __restrict__ Xadd,
                                                        float* __restrict__ Ofp) {
  __shared__ unsigned short Lds[2][2][2][8192];
  const int tid = threadIdx.x;
  const int w = tid >> 6, lane = tid & 63;
  const int wm = w >> 2, wn = w & 3;

  const int nbm = gridDim.x / nbn;
  const int xcd = blockIdx.x & 7;
  const int ib = blockIdx.x >> 3;
  int mt, nt;
  if ((nbm & 7) == 0) {
    const int mtpx = nbm >> 3;
    mt = xcd * mtpx + (ib % mtpx);
    nt = ib / mtpx;
  } else {
    const int ntpx = nbn >> 3;
    nt = xcd * ntpx + (ib % ntpx);
    mt = ib / ntpx;
  }
  const size_t m0 = (size_t)mt * 256, n0 = (size_t)nt * 256;

  const unsigned short* gA = A + (m0 + (lane >> 3)) * (size_t)K + ((lane & 7) ^ (lane >> 3)) * 8;
  const unsigned short* gB = B + (n0 + (lane >> 3)) * (size_t)K + ((lane & 7) ^ (lane >> 3)) * 8;
  const int wrow = w * 8;

  auto stageA = [&](int b, int h, int kt) {
    const unsigned short* g = gA + (size_t)(h * 128) * K + (size_t)kt * 64;
    GLDS(g + (size_t)wrow * K,        &Lds[0][b][h][wrow * 64]);
    GLDS(g + (size_t)(64 + wrow) * K, &Lds[0][b][h][(64 + wrow) * 64]);
  };
  auto stageB = [&](int b, int h, int kt) {
    const unsigned short* g = gB + (size_t)(h * 128) * K + (size_t)kt * 64;
    GLDS(g + (size_t)wrow * K,        &Lds[1][b][h][wrow * 64]);
    GLDS(g + (size_t)(64 + wrow) * K, &Lds[1][b][h][(64 + wrow) * 64]);
  };

  f32x4 acc[8][4];
#pragma unroll
  for (int i = 0; i < 8; ++i)
#pragma unroll
    for (int j = 0; j < 4; ++j) acc[i][j] = (f32x4){0.f, 0.f, 0.f, 0.f};

  const int KT = K >> 6;
  const int off_r = (lane & 15) * 64;
  const int slot0 = (((lane >> 4) ^ (lane & 7)) * 8);
  const int slot1 = slot0 ^ 32;
  const int boff = (wn & 1) * 4096;

  bf16x8 aLo[4][2], aHi[4][2], bLo[2][2], bHi[2][2];

  stageA(0, 0, 0); stageA(0, 1, 0); stageB(0, 0, 0); stageB(0, 1, 0);
  if (KT > 1) {
    stageB(1, 0, 1); stageB(1, 1, 1); stageA(1, 0, 1); stageA(1, 1, 1);
    VMC(8);
  } else {
    VMC(0);
  }
  BARF();

  int bb = 0;
  for (int t = 0; t < KT; ++t, bb ^= 1) {
    const unsigned short* Ab = &Lds[0][bb][wm][0];
    const unsigned short* Bb = &Lds[1][bb][wn >> 1][boff];

#pragma unroll
    for (int mi = 0; mi < 4; ++mi) {
      aLo[mi][0] = *(const bf16x8*)&Ab[mi * 1024 + off_r + slot0];
      aLo[mi][1] = *(const bf16x8*)&Ab[mi * 1024 + off_r + slot1];
    }
#pragma unroll
    for (int ni = 0; ni < 2; ++ni) {
      bLo[ni][0] = *(const bf16x8*)&Bb[ni * 1024 + off_r + slot0];
      bLo[ni][1] = *(const bf16x8*)&Bb[ni * 1024 + off_r + slot1];
      bHi[ni][0] = *(const bf16x8*)&Bb[(ni + 2) * 1024 + off_r + slot0];
      bHi[ni][1] = *(const bf16x8*)&Bb[(ni + 2) * 1024 + off_r + slot1];
    }

    __builtin_amdgcn_s_setprio(1);
#pragma unroll
    for (int mi = 0; mi < 4; ++mi)
#pragma unroll
      for (int ni = 0; ni < 2; ++ni)
#pragma unroll
        for (int ks = 0; ks < 2; ++ks)
          acc[mi][ni] = __builtin_amdgcn_mfma_f32_16x16x32_bf16(aLo[mi][ks], bLo[ni][ks], acc[mi][ni], 0, 0, 0);
    __builtin_amdgcn_s_setprio(0);

#pragma unroll
    for (int mi = 0; mi < 4; ++mi) {
      aHi[mi][0] = *(const bf16x8*)&Ab[(mi + 4) * 1024 + off_r + slot0];
      aHi[mi][1] = *(const bf16x8*)&Ab[(mi + 4) * 1024 + off_r + slot1];
    }

    __builtin_amdgcn_s_setprio(1);
#pragma unroll
    for (int mi = 0; mi < 4; ++mi)
#pragma unroll
      for (int ni = 0; ni < 2; ++ni)
#pragma unroll
        for (int ks = 0; ks < 2; ++ks)
          acc[mi][ni + 2] = __builtin_amdgcn_mfma_f32_16x16x32_bf16(aLo[mi][ks], bHi[ni][ks], acc[mi][ni + 2], 0, 0, 0);
    __builtin_amdgcn_s_setprio(0);
    BARF();

    if (t + 2 < KT) { stageB(bb, 0, t + 2); stageB(bb, 1, t + 2); }

    __builtin_amdgcn_s_setprio(1);
#pragma unroll
    for (int mi = 0; mi < 4; ++mi)
#pragma unroll
      for (int ni = 0; ni < 2; ++ni)
#pragma unroll
        for (int ks = 0; ks < 2; ++ks)
          acc[mi + 4][ni + 2] = __builtin_amdgcn_mfma_f32_16x16x32_bf16(aHi[mi][ks], bHi[ni][ks], acc[mi + 4][ni + 2], 0, 0, 0);
    __builtin_amdgcn_s_setprio(0);
    BARF();

    if (t + 2 < KT) { stageA(bb, 0, t + 2); stageA(bb, 1, t + 2); }

    __builtin_amdgcn_s_setprio(1);
#pragma unroll
    for (int mi = 0; mi < 4; ++mi)
#pragma unroll
      for (int ni = 0; ni < 2; ++ni)
#pragma unroll
        for (int ks = 0; ks < 2; ++ks)
          acc[mi + 4][ni] = __builtin_amdgcn_mfma_f32_16x16x32_bf16(aHi[mi][ks], bLo[ni][ks], acc[mi + 4][ni], 0, 0, 0);
    __builtin_amdgcn_s_setprio(0);

    if (t + 2 < KT) {
      VMC(8);
    } else {
      VMC(0);
    }
    BARF();
  }

  if (EPI == 0) {
    unsigned short* cw = &Lds[0][0][0][0] + (size_t)w * 8192;
#pragma unroll
    for (int mi = 0; mi < 8; ++mi)
#pragma unroll
      for (int ni = 0; ni < 4; ++ni)
#pragma unroll
        for (int r = 0; r < 4; ++r)
          cw[(mi * 16 + (lane >> 4) * 4 + r) * 64 + ni * 16 + (lane & 15)] = f2bf(acc[mi][ni][r]);
    const size_t gr0 = m0 + wm * 128;
    const size_t gc0 = n0 + wn * 64;
#pragma unroll
    for (int it = 0; it < 16; ++it) {
      int idx = it * 64 + lane;
      int rr = idx >> 3, c8 = (idx & 7) * 8;
      *(u16x8*)&Obf[(gr0 + rr) * (size_t)ldo + gc0 + c8] = *(const u16x8*)&cw[rr * 64 + c8];
    }
  } else {
    const size_t mrow0 = m0 + wm * 128 + (lane >> 4) * 4;
    const size_t ncol0 = n0 + wn * 64 + (lane & 15);
#pragma unroll
    for (int mi = 0; mi < 8; ++mi)
#pragma unroll
      for (int ni = 0; ni < 4; ++ni)
#pragma unroll
        for (int r = 0; r < 4; ++r) {
          size_t o = (mrow0 + mi * 16 + r) * T_TOK + ncol0 + ni * 16;
          Ofp[o] = acc[mi][ni][r] + Xadd[o];
        }
  }
}

extern "C" void kernel_launch(void* const* d_in, const int* in_sizes, int n_in,
                              void* d_out, int out_size, void* d_ws, size_t ws_size,
                              hipStream_t stream) {
  const float* x     = (const float*)d_in[0];
  const float* w_qkv = (const float*)d_in[1];
  const float* w_out = (const float*)d_in[2];
  const float* gamma = (const float*)d_in[3];
  const float* beta  = (const float*)d_in[4];

  char* ws = (char*)d_ws;
  unsigned short* wqkv_bf = (unsigned short*)(ws);                       // 6,291,456 B
  unsigned short* wout_bf = (unsigned short*)(ws + 6291456);             // 2,097,152 B
  float* mu    = (float*)(ws + 8388608);                                 // 65,536 B
  float* rstd  = (float*)(ws + 8454144);                                 // 65,536 B
  float* ropeT = (float*)(ws + 8519680);                                 // 8,192 B
  unsigned short* normed = (unsigned short*)(ws + 8527872);              // 33,554,432 B
  unsigned short* aout   = (unsigned short*)(ws + 42082304);             // 33,554,432 B

  cvt_kernel<<<3072, 256, 0, stream>>>(w_qkv, wqkv_bf, 3072 * 1024 / 4);
  cvt_kernel<<<1024, 256, 0, stream>>>(w_out, wout_bf, 1024 * 1024 / 4);
  rope_tab_kernel<<<4, 256, 0, stream>>>(ropeT);
  ln_stats_kernel<<<256, 256, 0, stream>>>(x, mu, rstd);
  ln_tr_kernel<<<4096, 256, 0, stream>>>(x, mu, rstd, gamma, beta, normed);
  // fused QKV-proj + RoPE + attention: grid 8 xcd * 8 tt * 16 h = 1024
  qkvattn_kernel<<<1024, 512, 0, stream>>>(normed, wqkv_bf, ropeT, aout);
  // GEMM2': d_out (1024x16384) = w_out @ aout^T + x -> grid 4*64 = 256
  gemm8p_kernel<1><<<256, 512, 0, stream>>>(wout_bf, aout, nullptr, 0, 64, 1024,
                                            x, (float*)d_out);
}

// Round 12
// 200.264 us; speedup vs baseline: 1.2208x; 1.0276x over previous
//
#include <hip/hip_runtime.h>

#define T_TOK 16384
#define C_DIM 1024

typedef float f32x4 __attribute__((ext_vector_type(4)));
typedef float f32x16 __attribute__((ext_vector_type(16)));
typedef __bf16 bf16x8 __attribute__((ext_vector_type(8)));
typedef unsigned short u16x8 __attribute__((ext_vector_type(8)));
typedef unsigned short u16x4 __attribute__((ext_vector_type(4)));

__device__ __forceinline__ unsigned short f2bf(float f) {
  union { float f; unsigned u; } v; v.f = f;
  unsigned r = v.u + 0x7fffu + ((v.u >> 16) & 1u);
  return (unsigned short)(r >> 16);
}
__device__ __forceinline__ float bf2f(unsigned short h) {
  union { unsigned u; float f; } v; v.u = ((unsigned)h) << 16;
  return v.f;
}
__device__ __forceinline__ unsigned pk2(float a, float b) {
  return (unsigned)f2bf(a) | ((unsigned)f2bf(b) << 16);
}

// ---------------- f32 -> bf16 weight conversion ----------------
__global__ __launch_bounds__(256) void cvt_kernel(const float* __restrict__ in,
                                                  unsigned short* __restrict__ out, int n4) {
  int i = blockIdx.x * 256 + threadIdx.x;
  if (i >= n4) return;
  f32x4 v = *(const f32x4*)(in + (size_t)i * 4);
  u16x4 o;
#pragma unroll
  for (int j = 0; j < 4; ++j) o[j] = f2bf(v[j]);
  *(u16x4*)(out + (size_t)i * 4) = o;
}

// ---------------- RoPE table: [32 pos][32 dmod] float2 (cos,sin) ----------------
__global__ __launch_bounds__(256) void rope_tab_kernel(float* __restrict__ tab) {
  int idx = blockIdx.x * 256 + threadIdx.x;
  if (idx >= 1024) return;
  int mm = idx >> 5, d = idx & 31;
  float invf = powf(10000.f, -(float)d * (1.f / 32.f));
  float ang = (float)mm * invf;
  float s, c;
  sincosf(ang, &s, &c);
  tab[idx * 2] = c;
  tab[idx * 2 + 1] = s;
}

// ---------------- single-pass LayerNorm + transpose ----------------
// One block = 32 tokens x all 1024 channels. Phase1: read x (C,T) into f32 LDS
// tile[1024][33] while accumulating per-token sum/sumsq (8 channel-groups).
// Phase2: normalize from LDS, write normed (T,C) bf16 with 128B-run stores.
// All-f32 stats path: numerics identical to the two-kernel version.
__global__ __launch_bounds__(256) void ln_fused_kernel(const float* __restrict__ x,
                                                       const float* __restrict__ gamma,
                                                       const float* __restrict__ beta,
                                                       unsigned short* __restrict__ normed) {
  __shared__ float tile[1024][33];
  __shared__ float s1[8][32], s2[8][32];
  __shared__ float ms[32], rs[32];
  const int tid = threadIdx.x;
  const int t0 = blockIdx.x * 32;

  // phase 1: tok = tid&31, g = tid>>5 covers channels g*128..g*128+127
  {
    const int tok = tid & 31, g = tid >> 5;
    float s = 0.f, ss = 0.f;
    const float* p = x + (size_t)(g * 128) * T_TOK + t0 + tok;
#pragma unroll 4
    for (int i = 0; i < 128; ++i) {
      float v = p[(size_t)i * T_TOK];
      tile[g * 128 + i][tok] = v;
      s += v; ss += v * v;
    }
    s1[g][tok] = s; s2[g][tok] = ss;
  }
  __syncthreads();
  if (tid < 32) {
    float S = 0.f, SS = 0.f;
#pragma unroll
    for (int g = 0; g < 8; ++g) { S += s1[g][tid]; SS += s2[g][tid]; }
    float m = S * (1.f / 1024.f);
    float var = SS * (1.f / 1024.f) - m * m;
    ms[tid] = m;
    rs[tid] = rsqrtf(var + 1e-5f);
  }
  __syncthreads();

  // phase 2: tok = tid>>3, cg = tid&7; wave covers 8 toks x 64 contiguous ch
  {
    const int tok = tid >> 3, cg = tid & 7;
    const float m = ms[tok], rr = rs[tok];
#pragma unroll
    for (int i = 0; i < 16; ++i) {
      int ch8 = cg * 8 + i * 64;
      u16x8 o;
#pragma unroll
      for (int j = 0; j < 8; ++j) {
        float v = tile[ch8 + j][tok];
        o[j] = f2bf((v - m) * rr * gamma[ch8 + j] + beta[ch8 + j]);
      }
      *(u16x8*)&normed[(size_t)(t0 + tok) * C_DIM + ch8] = o;
    }
  }
}

#define GLDS(gp, lp) \
  __builtin_amdgcn_global_load_lds((const __attribute__((address_space(1))) void*)(gp), \
                                   (__attribute__((address_space(3))) void*)(lp), 16, 0, 0)

#define BARF() do { __builtin_amdgcn_s_barrier(); asm volatile("" ::: "memory"); } while (0)
#define VMC(n) asm volatile("s_waitcnt vmcnt(" #n ")" ::: "memory")

// ======== fused QKV-projection + RoPE + windowed attention ========
// One block = (256-token tile tt) x (head h). 512 thr = 8 waves (4M x 2N);
// per-wave C: 64x96. K-loop uses the R8 quadrant-interleaved schedule:
//   reads aLo+bLo+bHi -> q0 -> reads aHi -> q1 -> BARF -> stageB(t+2,cur) ->
//   q2 -> BARF -> stageA(t+2,cur) -> q3 -> VMC(7) -> BARF.
// Lifetimes: stageB legal after q1-BARF (bLo/bHi ds_reads consumed by q0/q1);
// stageA after q2-BARF (aHi consumed by q2). FIFO at VMC(7): t+1's 7 + t+2's 7
// = 14 outstanding, keep 7 -> tile t+1 fully landed.
__global__ __launch_bounds__(512, 2) void qkvattn_kernel(const unsigned short* __restrict__ A,
                                                         const unsigned short* __restrict__ Bq,
                                                         const float* __restrict__ ropeT,
                                                         unsigned short* __restrict__ aout) {
  __shared__ unsigned short arena[57344];  // 114,688 B
  unsigned short* LA = arena;              // [2][256*64]
  unsigned short* LB = arena + 32768;      // [2][192*64]
  unsigned short* QKl = arena;             // epilogue: [256][136]
  unsigned short* Vtl = arena + 34816;     // epilogue: [8][64][32]

  const int tid = threadIdx.x;
  const int w = tid >> 6, lane = tid & 63;
  const int wm = w >> 1, wn = w & 1;
  const int K = 1024, KT = 16;

  const int xcd = blockIdx.x & 7;
  const int ib = blockIdx.x >> 3;
  const int tt = xcd * 8 + (ib & 7);
  const int h = ib >> 3;
  const size_t m0 = (size_t)tt * 256;

  const int preslot = ((lane & 7) ^ (lane >> 3)) * 8;
  const unsigned short* gA = A + (m0 + w * 8 + (lane >> 3)) * (size_t)K + preslot;
  const unsigned short* gB0 = Bq + ((size_t)(0 + h * 64 + w * 8 + (lane >> 3))) * K + preslot;
  const unsigned short* gB1 = Bq + ((size_t)(1024 + h * 64 + w * 8 + (lane >> 3))) * K + preslot;
  const unsigned short* gB2 = Bq + ((size_t)(2048 + h * 64 + w * 8 + (lane >> 3))) * K + preslot;

  auto stageA4 = [&](int b, int kt) {
    const size_t k0 = (size_t)kt * 64;
    GLDS(gA + k0,                   LA + b * 16384 + (w * 8) * 64);
    GLDS(gA + (size_t)64 * K + k0,  LA + b * 16384 + (64 + w * 8) * 64);
    GLDS(gA + (size_t)128 * K + k0, LA + b * 16384 + (128 + w * 8) * 64);
    GLDS(gA + (size_t)192 * K + k0, LA + b * 16384 + (192 + w * 8) * 64);
  };
  auto stageB3 = [&](int b, int kt) {
    const size_t k0 = (size_t)kt * 64;
    GLDS(gB0 + k0, LB + b * 12288 + (w * 8) * 64);
    GLDS(gB1 + k0, LB + b * 12288 + (64 + w * 8) * 64);
    GLDS(gB2 + k0, LB + b * 12288 + (128 + w * 8) * 64);
  };

  f32x4 acc[4][6];
#pragma unroll
  for (int i = 0; i < 4; ++i)
#pragma unroll
    for (int j = 0; j < 6; ++j) acc[i][j] = (f32x4){0.f, 0.f, 0.f, 0.f};

  const int off_r = (lane & 15) * 64;
  const int slot0 = (((lane >> 4) ^ (lane & 7)) * 8);
  const int slot1 = slot0 ^ 32;

  bf16x8 aF[4][2], bF[6][2];

  // ---- prologue: stage t0 + t1; VMC(7) -> t0 landed ----
  stageA4(0, 0); stageB3(0, 0);
  stageA4(1, 1); stageB3(1, 1);
  VMC(7);
  BARF();

  int bb = 0;
  for (int t = 0; t < KT; ++t, bb ^= 1) {
    const unsigned short* Ab = LA + bb * 16384 + (wm * 64) * 64;
    const unsigned short* Bb = LB + bb * 12288 + (wn * 96) * 64;

    // ---- reads: aF[0..1] + all bF (compiler counts the waits) ----
#pragma unroll
    for (int mi = 0; mi < 2; ++mi) {
      aF[mi][0] = *(const bf16x8*)&Ab[mi * 1024 + off_r + slot0];
      aF[mi][1] = *(const bf16x8*)&Ab[mi * 1024 + off_r + slot1];
    }
#pragma unroll
    for (int ni = 0; ni < 6; ++ni) {
      bF[ni][0] = *(const bf16x8*)&Bb[ni * 1024 + off_r + slot0];
      bF[ni][1] = *(const bf16x8*)&Bb[ni * 1024 + off_r + slot1];
    }

    // ---- q0: mi0-1 x ni0-2 ----
    __builtin_amdgcn_s_setprio(1);
#pragma unroll
    for (int mi = 0; mi < 2; ++mi)
#pragma unroll
      for (int ni = 0; ni < 3; ++ni)
#pragma unroll
        for (int ks = 0; ks < 2; ++ks)
          acc[mi][ni] = __builtin_amdgcn_mfma_f32_16x16x32_bf16(aF[mi][ks], bF[ni][ks], acc[mi][ni], 0, 0, 0);
    __builtin_amdgcn_s_setprio(0);

    // ---- reads: aF[2..3] (drain under q1) ----
#pragma unroll
    for (int mi = 2; mi < 4; ++mi) {
      aF[mi][0] = *(const bf16x8*)&Ab[mi * 1024 + off_r + slot0];
      aF[mi][1] = *(const bf16x8*)&Ab[mi * 1024 + off_r + slot1];
    }

    // ---- q1: mi0-1 x ni3-5 ----
    __builtin_amdgcn_s_setprio(1);
#pragma unroll
    for (int mi = 0; mi < 2; ++mi)
#pragma unroll
      for (int ni = 3; ni < 6; ++ni)
#pragma unroll
        for (int ks = 0; ks < 2; ++ks)
          acc[mi][ni] = __builtin_amdgcn_mfma_f32_16x16x32_bf16(aF[mi][ks], bF[ni][ks], acc[mi][ni], 0, 0, 0);
    __builtin_amdgcn_s_setprio(0);
    BARF();  // all waves' B ds_reads retired -> B region stageable

    if (t + 2 < KT) stageB3(bb, t + 2);

    // ---- q2: mi2-3 x ni3-5 ----
    __builtin_amdgcn_s_setprio(1);
#pragma unroll
    for (int mi = 2; mi < 4; ++mi)
#pragma unroll
      for (int ni = 3; ni < 6; ++ni)
#pragma unroll
        for (int ks = 0; ks < 2; ++ks)
          acc[mi][ni] = __builtin_amdgcn_mfma_f32_16x16x32_bf16(aF[mi][ks], bF[ni][ks], acc[mi][ni], 0, 0, 0);
    __builtin_amdgcn_s_setprio(0);
    BARF();  // all waves' A ds_reads retired -> A region stageable

    if (t + 2 < KT) stageA4(bb, t + 2);

    // ---- q3: mi2-3 x ni0-2 ----
    __builtin_amdgcn_s_setprio(1);
#pragma unroll
    for (int mi = 2; mi < 4; ++mi)
#pragma unroll
      for (int ni = 0; ni < 3; ++ni)
#pragma unroll
        for (int ks = 0; ks < 2; ++ks)
          acc[mi][ni] = __builtin_amdgcn_mfma_f32_16x16x32_bf16(aF[mi][ks], bF[ni][ks], acc[mi][ni], 0, 0, 0);
    __builtin_amdgcn_s_setprio(0);

    if (t + 2 < KT) {
      VMC(7);
    } else {
      VMC(0);
    }
    BARF();
  }

  // ---- epilogue: repack C frags -> QKl [256][136] (q|k), Vtl [8][64][32] (v) ----
  __syncthreads();
#pragma unroll
  for (int mi = 0; mi < 4; ++mi)
#pragma unroll
    for (int ni = 0; ni < 6; ++ni) {
      const int j = wn * 96 + ni * 16 + (lane & 15);
#pragma unroll
      for (int r = 0; r < 4; ++r) {
        int tok = wm * 64 + mi * 16 + (lane >> 4) * 4 + r;
        unsigned short bv = f2bf(acc[mi][ni][r]);
        if (wn == 0 || ni < 2) {
          QKl[tok * 136 + j] = bv;
        } else {
          int d = j - 128;
          int mm = tok & 31, win = tok >> 5;
          Vtl[(win * 64 + d) * 32 + ((((mm >> 3) ^ (d ^ (d >> 2))) & 3) * 8 + (mm & 7))] = bv;
        }
      }
    }
  __syncthreads();

  // ---- per-wave window attention (wave w = window w of this tile) ----
  {
    const int m = lane & 31, hi = lane >> 5;
    const unsigned short* qp = QKl + (size_t)(w * 32 + m) * 136;
    u16x8 qv[4], kv[4];
#pragma unroll
    for (int s = 0; s < 4; ++s) {
      int off = s * 16 + hi * 8;
      qv[s] = *(const u16x8*)(qp + off);
      kv[s] = *(const u16x8*)(qp + 64 + off);
    }

    f32x4 ct[2][4];
    const float* tp = ropeT + (size_t)(m * 32 + hi * 8) * 2;
#pragma unroll
    for (int kp = 0; kp < 2; ++kp)
#pragma unroll
      for (int q = 0; q < 4; ++q)
        ct[kp][q] = *(const f32x4*)(tp + kp * 32 + q * 4);

    union FU { unsigned u[4]; bf16x8 v; };
    bf16x8 qfr[4], kfr[4];
#pragma unroll
    for (int ks = 0; ks < 4; ++ks) {
      const int kp = ks & 1;
      FU fq, fk;
#pragma unroll
      for (int jp = 0; jp < 4; ++jp) {
        float c0 = ct[kp][jp][0], s0 = ct[kp][jp][1];
        float c1 = ct[kp][jp][2], s1 = ct[kp][jp][3];
        float q0 = bf2f(qv[ks][2 * jp]), q1 = bf2f(qv[ks][2 * jp + 1]);
        float k0 = bf2f(kv[ks][2 * jp]), k1 = bf2f(kv[ks][2 * jp + 1]);
        float rq0, rq1, rk0, rk1;
        if (ks < 2) {
          rq0 = -bf2f(qv[ks + 2][2 * jp]); rq1 = -bf2f(qv[ks + 2][2 * jp + 1]);
          rk0 = -bf2f(kv[ks + 2][2 * jp]); rk1 = -bf2f(kv[ks + 2][2 * jp + 1]);
        } else {
          rq0 = bf2f(qv[ks - 2][2 * jp]); rq1 = bf2f(qv[ks - 2][2 * jp + 1]);
          rk0 = bf2f(kv[ks - 2][2 * jp]); rk1 = bf2f(kv[ks - 2][2 * jp + 1]);
        }
        fq.u[jp] = pk2(q0 * c0 + rq0 * s0, q1 * c1 + rq1 * s1);
        fk.u[jp] = pk2(k0 * c0 + rk0 * s0, k1 * c1 + rk1 * s1);
      }
      qfr[ks] = fq.v; kfr[ks] = fk.v;
    }

    f32x16 accS;
#pragma unroll
    for (int i = 0; i < 16; ++i) accS[i] = 0.f;
#pragma unroll
    for (int ks = 0; ks < 4; ++ks)
      accS = __builtin_amdgcn_mfma_f32_32x32x16_bf16(kfr[ks], qfr[ks], accS, 0, 0, 0);

    float p[16];
    float mx = -1e30f;
#pragma unroll
    for (int r = 0; r < 16; ++r) { p[r] = accS[r] * 0.125f; mx = fmaxf(mx, p[r]); }
    mx = fmaxf(mx, __shfl_xor(mx, 32, 64));
    float sum = 0.f;
#pragma unroll
    for (int r = 0; r < 16; ++r) { p[r] = __expf(p[r] - mx); sum += p[r]; }
    sum += __shfl_xor(sum, 32, 64);
    const float inv = 1.f / sum;
#pragma unroll
    for (int r = 0; r < 16; ++r) p[r] *= inv;

    bf16x8 pfr[2];
    {
      FU f0, f1;
      unsigned a0 = hi ? pk2(p[0], p[1]) : pk2(p[4], p[5]);
      unsigned a1 = hi ? pk2(p[2], p[3]) : pk2(p[6], p[7]);
      unsigned b0 = (unsigned)__shfl_xor((int)a0, 32, 64);
      unsigned b1 = (unsigned)__shfl_xor((int)a1, 32, 64);
      if (hi) { f0.u[0] = b0; f0.u[1] = b1; f0.u[2] = pk2(p[4], p[5]); f0.u[3] = pk2(p[6], p[7]); }
      else    { f0.u[0] = pk2(p[0], p[1]); f0.u[1] = pk2(p[2], p[3]); f0.u[2] = b0; f0.u[3] = b1; }
      unsigned a2 = hi ? pk2(p[8], p[9])   : pk2(p[12], p[13]);
      unsigned a3 = hi ? pk2(p[10], p[11]) : pk2(p[14], p[15]);
      unsigned b2 = (unsigned)__shfl_xor((int)a2, 32, 64);
      unsigned b3 = (unsigned)__shfl_xor((int)a3, 32, 64);
      if (hi) { f1.u[0] = b2; f1.u[1] = b3; f1.u[2] = pk2(p[12], p[13]); f1.u[3] = pk2(p[14], p[15]); }
      else    { f1.u[0] = pk2(p[8], p[9]); f1.u[1] = pk2(p[10], p[11]); f1.u[2] = b2; f1.u[3] = b3; }
      pfr[0] = f0.v; pfr[1] = f1.v;
    }

    f32x16 accO[2];
#pragma unroll
    for (int i = 0; i < 16; ++i) { accO[0][i] = 0.f; accO[1][i] = 0.f; }
    const int dl = lane & 31;
#pragma unroll
    for (int dh = 0; dh < 2; ++dh) {
      int d = dh * 32 + dl;
      int sx = (d ^ (d >> 2)) & 3;
#pragma unroll
      for (int ks = 0; ks < 2; ++ks) {
        bf16x8 vf = *(const bf16x8*)&Vtl[(w * 64 + d) * 32 + (((2 * ks + hi) ^ sx) & 3) * 8];
        accO[dh] = __builtin_amdgcn_mfma_f32_32x32x16_bf16(pfr[ks], vf, accO[dh], 0, 0, 0);
      }
    }

    const int W = tt * 8 + w;
#pragma unroll
    for (int r = 0; r < 16; ++r) {
      int n = (r & 3) + 8 * (r >> 2) + 4 * hi;
      size_t o = (size_t)(W * 32 + n) * 1024 + h * 64 + dl;
      aout[o] = f2bf(accO[0][r]);
      aout[o + 32] = f2bf(accO[1][r]);
    }
  }
}

// ================= 256x256 compiler-pipelined bf16 NT GEMM (GEMM2') =================
template <int EPI>
__global__ __launch_bounds__(512, 2) void gemm8p_kernel(const unsigned short* __restrict__ A,
                                                        const unsigned short* __restrict__ B,
                                                        unsigned short* __restrict__ Obf,
                                                        int ldo, int nbn, int K,
                                                        const float* __restrict__ Xadd,
                                                        float* __restrict__ Ofp) {
  __shared__ unsigned short Lds[2][2][2][8192];
  const int tid = threadIdx.x;
  const int w = tid >> 6, lane = tid & 63;
  const int wm = w >> 2, wn = w & 3;

  const int nbm = gridDim.x / nbn;
  const int xcd = blockIdx.x & 7;
  const int ib = blockIdx.x >> 3;
  int mt, nt;
  if ((nbm & 7) == 0) {
    const int mtpx = nbm >> 3;
    mt = xcd * mtpx + (ib % mtpx);
    nt = ib / mtpx;
  } else {
    const int ntpx = nbn >> 3;
    nt = xcd * ntpx + (ib % ntpx);
    mt = ib / ntpx;
  }
  const size_t m0 = (size_t)mt * 256, n0 = (size_t)nt * 256;

  const unsigned short* gA = A + (m0 + (lane >> 3)) * (size_t)K + ((lane & 7) ^ (lane >> 3)) * 8;
  const unsigned short* gB = B + (n0 + (lane >> 3)) * (size_t)K + ((lane & 7) ^ (lane >> 3)) * 8;
  const int wrow = w * 8;

  auto stageA = [&](int b, int h, int kt) {
    const unsigned short* g = gA + (size_t)(h * 128) * K + (size_t)kt * 64;
    GLDS(g + (size_t)wrow * K,        &Lds[0][b][h][wrow * 64]);
    GLDS(g + (size_t)(64 + wrow) * K, &Lds[0][b][h][(64 + wrow) * 64]);
  };
  auto stageB = [&](int b, int h, int kt) {
    const unsigned short* g = gB + (size_t)(h * 128) * K + (size_t)kt * 64;
    GLDS(g + (size_t)wrow * K,        &Lds[1][b][h][wrow * 64]);
    GLDS(g + (size_t)(64 + wrow) * K, &Lds[1][b][h][(64 + wrow) * 64]);
  };

  f32x4 acc[8][4];
#pragma unroll
  for (int i = 0; i < 8; ++i)
#pragma unroll
    for (int j = 0; j < 4; ++j) acc[i][j] = (f32x4){0.f, 0.f, 0.f, 0.f};

  const int KT = K >> 6;
  const int off_r = (lane & 15) * 64;
  const int slot0 = (((lane >> 4) ^ (lane & 7)) * 8);
  const int slot1 = slot0 ^ 32;
  const int boff = (wn & 1) * 4096;

  bf16x8 aLo[4][2], aHi[4][2], bLo[2][2], bHi[2][2];

  stageA(0, 0, 0); stageA(0, 1, 0); stageB(0, 0, 0); stageB(0, 1, 0);
  if (KT > 1) {
    stageB(1, 0, 1); stageB(1, 1, 1); stageA(1, 0, 1); stageA(1, 1, 1);
    VMC(8);
  } else {
    VMC(0);
  }
  BARF();

  int bb = 0;
  for (int t = 0; t < KT; ++t, bb ^= 1) {
    const unsigned short* Ab = &Lds[0][bb][wm][0];
    const unsigned short* Bb = &Lds[1][bb][wn >> 1][boff];

#pragma unroll
    for (int mi = 0; mi < 4; ++mi) {
      aLo[mi][0] = *(const bf16x8*)&Ab[mi * 1024 + off_r + slot0];
      aLo[mi][1] = *(const bf16x8*)&Ab[mi * 1024 + off_r + slot1];
    }
#pragma unroll
    for (int ni = 0; ni < 2; ++ni) {
      bLo[ni][0] = *(const bf16x8*)&Bb[ni * 1024 + off_r + slot0];
      bLo[ni][1] = *(const bf16x8*)&Bb[ni * 1024 + off_r + slot1];
      bHi[ni][0] = *(const bf16x8*)&Bb[(ni + 2) * 1024 + off_r + slot0];
      bHi[ni][1] = *(const bf16x8*)&Bb[(ni + 2) * 1024 + off_r + slot1];
    }

    __builtin_amdgcn_s_setprio(1);
#pragma unroll
    for (int mi = 0; mi < 4; ++mi)
#pragma unroll
      for (int ni = 0; ni < 2; ++ni)
#pragma unroll
        for (int ks = 0; ks < 2; ++ks)
          acc[mi][ni] = __builtin_amdgcn_mfma_f32_16x16x32_bf16(aLo[mi][ks], bLo[ni][ks], acc[mi][ni], 0, 0, 0);
    __builtin_amdgcn_s_setprio(0);

#pragma unroll
    for (int mi = 0; mi < 4; ++mi) {
      aHi[mi][0] = *(const bf16x8*)&Ab[(mi + 4) * 1024 + off_r + slot0];
      aHi[mi][1] = *(const bf16x8*)&Ab[(mi + 4) * 1024 + off_r + slot1];
    }

    __builtin_amdgcn_s_setprio(1);
#pragma unroll
    for (int mi = 0; mi < 4; ++mi)
#pragma unroll
      for (int ni = 0; ni < 2; ++ni)
#pragma unroll
        for (int ks = 0; ks < 2; ++ks)
          acc[mi][ni + 2] = __builtin_amdgcn_mfma_f32_16x16x32_bf16(aLo[mi][ks], bHi[ni][ks], acc[mi][ni + 2], 0, 0, 0);
    __builtin_amdgcn_s_setprio(0);
    BARF();

    if (t + 2 < KT) { stageB(bb, 0, t + 2); stageB(bb, 1, t + 2); }

    __builtin_amdgcn_s_setprio(1);
#pragma unroll
    for (int mi = 0; mi < 4; ++mi)
#pragma unroll
      for (int ni = 0; ni < 2; ++ni)
#pragma unroll
        for (int ks = 0; ks < 2; ++ks)
          acc[mi + 4][ni + 2] = __builtin_amdgcn_mfma_f32_16x16x32_bf16(aHi[mi][ks], bHi[ni][ks], acc[mi + 4][ni + 2], 0, 0, 0);
    __builtin_amdgcn_s_setprio(0);
    BARF();

    if (t + 2 < KT) { stageA(bb, 0, t + 2); stageA(bb, 1, t + 2); }

    __builtin_amdgcn_s_setprio(1);
#pragma unroll
    for (int mi = 0; mi < 4; ++mi)
#pragma unroll
      for (int ni = 0; ni < 2; ++ni)
#pragma unroll
        for (int ks = 0; ks < 2; ++ks)
          acc[mi + 4][ni] = __builtin_amdgcn_mfma_f32_16x16x32_bf16(aHi[mi][ks], bLo[ni][ks], acc[mi + 4][ni], 0, 0, 0);
    __builtin_amdgcn_s_setprio(0);

    if (t + 2 < KT) {
      VMC(8);
    } else {
      VMC(0);
    }
    BARF();
  }

  if (EPI == 0) {
    unsigned short* cw = &Lds[0][0][0][0] + (size_t)w * 8192;
#pragma unroll
    for (int mi = 0; mi < 8; ++mi)
#pragma unroll
      for (int ni = 0; ni < 4; ++ni)
#pragma unroll
        for (int r = 0; r < 4; ++r)
          cw[(mi * 16 + (lane >> 4) * 4 + r) * 64 + ni * 16 + (lane & 15)] = f2bf(acc[mi][ni][r]);
    const size_t gr0 = m0 + wm * 128;
    const size_t gc0 = n0 + wn * 64;
#pragma unroll
    for (int it = 0; it < 16; ++it) {
      int idx = it * 64 + lane;
      int rr = idx >> 3, c8 = (idx & 7) * 8;
      *(u16x8*)&Obf[(gr0 + rr) * (size_t)ldo + gc0 + c8] = *(const u16x8*)&cw[rr * 64 + c8];
    }
  } else {
    const size_t mrow0 = m0 + wm * 128 + (lane >> 4) * 4;
    const size_t ncol0 = n0 + wn * 64 + (lane & 15);
#pragma unroll
    for (int mi = 0; mi < 8; ++mi)
#pragma unroll
      for (int ni = 0; ni < 4; ++ni)
#pragma unroll
        for (int r = 0; r < 4; ++r) {
          size_t o = (mrow0 + mi * 16 + r) * T_TOK + ncol0 + ni * 16;
          Ofp[o] = acc[mi][ni][r] + Xadd[o];
        }
  }
}

extern "C" void kernel_launch(void* const* d_in, const int* in_sizes, int n_in,
                              void* d_out, int out_size, void* d_ws, size_t ws_size,
                              hipStream_t stream) {
  const float* x     = (const float*)d_in[0];
  const float* w_qkv = (const float*)d_in[1];
  const float* w_out = (const float*)d_in[2];
  const float* gamma = (const float*)d_in[3];
  const float* beta  = (const float*)d_in[4];

  char* ws = (char*)d_ws;
  unsigned short* wqkv_bf = (unsigned short*)(ws);                       // 6,291,456 B
  unsigned short* wout_bf = (unsigned short*)(ws + 6291456);             // 2,097,152 B
  float* ropeT = (float*)(ws + 8519680);                                 // 8,192 B
  unsigned short* normed = (unsigned short*)(ws + 8527872);              // 33,554,432 B
  unsigned short* aout   = (unsigned short*)(ws + 42082304);             // 33,554,432 B

  cvt_kernel<<<3072, 256, 0, stream>>>(w_qkv, wqkv_bf, 3072 * 1024 / 4);
  cvt_kernel<<<1024, 256, 0, stream>>>(w_out, wout_bf, 1024 * 1024 / 4);
  rope_tab_kernel<<<4, 256, 0, stream>>>(ropeT);
  // single-pass LayerNorm + transpose: grid 512 (32 tokens each)
  ln_fused_kernel<<<512, 256, 0, stream>>>(x, gamma, beta, normed);
  // fused QKV-proj + RoPE + attention: grid 8 xcd * 8 tt * 16 h = 1024
  qkvattn_kernel<<<1024, 512, 0, stream>>>(normed, wqkv_bf, ropeT, aout);
  // GEMM2': d_out (1024x16384) = w_out @ aout^T + x -> grid 4*64 = 256
  gemm8p_kernel<1><<<256, 512, 0, stream>>>(wout_bf, aout, nullptr, 0, 64, 1024,
                                            x, (float*)d_out);
}